// Round 2
// baseline (6116.539 us; speedup 1.0000x reference)
//
#include <hip/hip_runtime.h>
#include <hip/hip_bf16.h>

typedef __hip_bfloat16 bf16;

constexpr int NB   = 4;
constexpr int H    = 128;
constexpr int W    = 128;
constexpr int HW   = H * W;
constexpr int NPIX = NB * HW;        // 65536
constexpr int CCAT = 384;
constexpr int CSKIP= 128;
constexpr int CIN  = 256;
constexpr int CO   = 128;
constexpr int HS   = 64;             // source spatial for upsample
constexpr float EPS = 1e-5f;

__device__ __forceinline__ float b2f(bf16 v){ return __bfloat162float(v); }
__device__ __forceinline__ bf16  f2b(float v){ return __float2bfloat16(v); }

// ---------------- zero small stat buffers ----------------
__global__ void k_zero(float* p, int n){
    int i = blockIdx.x * blockDim.x + threadIdx.x;
    if (i < n) p[i] = 0.f;
}

// ------------- build cat = [skip ; upsample2x(x)] in NHWC bf16 -------------
// inputs are fp32 NCHW
__global__ void k_build_cat(const float* __restrict__ x, const float* __restrict__ skip,
                            bf16* __restrict__ cat){
    int i = blockIdx.x * blockDim.x + threadIdx.x;
    if (i >= NPIX * CCAT) return;
    int c   = i % CCAT;
    int pix = i / CCAT;
    int xx  = pix % W;
    int yy  = (pix / W) % H;
    int b   = pix / HW;
    float v;
    if (c < CSKIP) {
        v = skip[((b * CSKIP + c) * H + yy) * W + xx];
    } else {
        int ic = c - CSKIP;
        // align_corners=True: src = i*(Lin-1)/(Lout-1) = i*63/127
        float cy = (yy * 63.0f) / 127.0f;
        float cx = (xx * 63.0f) / 127.0f;
        int y0 = (int)cy, x0 = (int)cx;
        int y1 = min(y0 + 1, HS - 1), x1 = min(x0 + 1, HS - 1);
        float wy = cy - y0, wx = cx - x0;
        const float* xb = x + ((size_t)(b * CIN + ic) * HS) * HS;
        float v00 = xb[y0 * HS + x0];
        float v01 = xb[y0 * HS + x1];
        float v10 = xb[y1 * HS + x0];
        float v11 = xb[y1 * HS + x1];
        v = v00 * (1 - wy) * (1 - wx) + v01 * (1 - wy) * wx
          + v10 * wy * (1 - wx)       + v11 * wy * wx;
    }
    cat[i] = f2b(v);
}

// ------------- weight transposes (OIHW fp32 -> [k][ic][oc] fp32) -------------
__global__ void k_tr_w1(const float* __restrict__ w, float* __restrict__ wt){
    int i = blockIdx.x * blockDim.x + threadIdx.x;
    if (i >= 9 * CCAT * CO) return;
    int oc = i % CO; int r = i / CO; int ic = r % CCAT; int kk = r / CCAT;
    wt[i] = w[(oc * CCAT + ic) * 9 + kk];
}
__global__ void k_tr_off(const float* __restrict__ w, float* __restrict__ wt){
    int i = blockIdx.x * blockDim.x + threadIdx.x;
    if (i >= 9 * CO * 18) return;
    int oc = i % 18; int r = i / 18; int ic = r % CO; int kk = r / CO;
    wt[i] = w[(oc * CO + ic) * 9 + kk];
}
__global__ void k_tr_def(const float* __restrict__ w, float* __restrict__ wt){
    int i = blockIdx.x * blockDim.x + threadIdx.x;
    if (i >= CO * 9 * CO) return;
    int o = i % CO; int r = i / CO;      // r = c*9+k
    int c = r / 9,  k = r % 9;
    wt[i] = w[(o * CO + c) * 9 + k];
}

// ------------- conv1: cat(NHWC,384) -> c1(NHWC,128), 3x3 pad1, fp32 accum -------------
__global__ __launch_bounds__(128) void k_conv1(const bf16* __restrict__ cat,
                                               const float* __restrict__ wt,
                                               bf16* __restrict__ c1){
    int oc  = threadIdx.x;                 // 0..127
    int tile= blockIdx.x;                  // b*H*(W/16)
    int xt  = tile % (W / 16);
    int yy  = (tile / (W / 16)) % H;
    int b   = tile / ((W / 16) * H);
    int x0  = xt * 16;
    float acc[16];
#pragma unroll
    for (int p = 0; p < 16; p++) acc[p] = 0.f;
    for (int ky = 0; ky < 3; ky++){
        int row = yy + ky - 1;
        if (row < 0 || row >= H) continue;
        const bf16* inrow = cat + (size_t)(b * HW + row * W) * CCAT;
        const float* wk   = wt + ky * 3 * CCAT * CO;
        for (int ic = 0; ic < CCAT; ic++){
            float in[18];
#pragma unroll
            for (int j = 0; j < 18; j++){
                int xx = x0 - 1 + j;
                in[j] = (xx >= 0 && xx < W) ? b2f(inrow[xx * CCAT + ic]) : 0.f;
            }
            float w0 = wk[(0 * CCAT + ic) * CO + oc];
            float w1 = wk[(1 * CCAT + ic) * CO + oc];
            float w2 = wk[(2 * CCAT + ic) * CO + oc];
#pragma unroll
            for (int p = 0; p < 16; p++)
                acc[p] += in[p] * w0 + in[p + 1] * w1 + in[p + 2] * w2;
        }
    }
    bf16* orow = c1 + (size_t)(b * HW + yy * W + x0) * CO;
#pragma unroll
    for (int p = 0; p < 16; p++) orow[p * CO + oc] = f2b(acc[p]);
}

// ------------- BN stats: per-channel sum & sumsq over NHWC [NPIX,128] -------------
__global__ __launch_bounds__(256) void k_bn_stats(const bf16* __restrict__ t,
                                                  float* __restrict__ sums){
    int c    = threadIdx.x & 127;
    int half = threadIdx.x >> 7;            // 0/1
    int pix0 = blockIdx.x * 256;
    float s = 0.f, q = 0.f;
    for (int p = half; p < 256; p += 2){
        float v = b2f(t[(size_t)(pix0 + p) * CO + c]);
        s += v; q += v * v;
    }
    __shared__ float ls[256], lq[256];
    ls[threadIdx.x] = s; lq[threadIdx.x] = q;
    __syncthreads();
    if (threadIdx.x < 128){
        atomicAdd(&sums[c],       ls[threadIdx.x] + ls[threadIdx.x + 128]);
        atomicAdd(&sums[128 + c], lq[threadIdx.x] + lq[threadIdx.x + 128]);
    }
}

__global__ void k_bn_fin(const float* __restrict__ sums, const float* __restrict__ g,
                         const float* __restrict__ bb, float* __restrict__ sc){
    int c = threadIdx.x;
    if (c >= CO) return;
    float n    = (float)NPIX;
    float mean = sums[c] / n;
    float var  = sums[128 + c] / n - mean * mean;
    float scale = g[c] * rsqrtf(var + EPS);
    sc[c]       = scale;
    sc[128 + c] = bb[c] - mean * scale;
}

// ------------- affine + relu, in place -------------
__global__ void k_bn_apply(bf16* __restrict__ t, const float* __restrict__ sc){
    int i = blockIdx.x * blockDim.x + threadIdx.x;
    if (i >= NPIX * CO) return;
    int c = i & 127;
    float v = b2f(t[i]) * sc[c] + sc[128 + c];
    t[i] = f2b(v > 0.f ? v : 0.f);
}

// ------------- offset conv: h(NHWC,128) -> off(NHWC,18), 3x3 pad1 + bias -------------
__global__ __launch_bounds__(128) void k_conv_off(const bf16* __restrict__ h,
                                                  const float* __restrict__ wt,
                                                  const float* __restrict__ off_b,
                                                  bf16* __restrict__ off){
    int x  = threadIdx.x;                   // 0..127
    int yy = blockIdx.x % H;
    int b  = blockIdx.x / H;
    float acc[18];
#pragma unroll
    for (int o = 0; o < 18; o++) acc[o] = off_b[o];
    for (int ky = 0; ky < 3; ky++){
        int row = yy + ky - 1;
        if (row < 0 || row >= H) continue;
        const bf16* hr = h + (size_t)(b * HW + row * W) * CO;
        for (int ic = 0; ic < CO; ic++){
            float in0 = (x - 1 >= 0) ? b2f(hr[(x - 1) * CO + ic]) : 0.f;
            float in1 = b2f(hr[x * CO + ic]);
            float in2 = (x + 1 < W)  ? b2f(hr[(x + 1) * CO + ic]) : 0.f;
            const float* wp = wt + ((ky * 3 + 0) * CO + ic) * 18;
#pragma unroll
            for (int o = 0; o < 18; o++) acc[o] += in0 * wp[o];
            wp += CO * 18;
#pragma unroll
            for (int o = 0; o < 18; o++) acc[o] += in1 * wp[o];
            wp += CO * 18;
#pragma unroll
            for (int o = 0; o < 18; o++) acc[o] += in2 * wp[o];
        }
    }
    bf16* op = off + (size_t)(b * HW + yy * W + x) * 18;
#pragma unroll
    for (int o = 0; o < 18; o++) op[o] = f2b(acc[o]);
}

// ------------- deform sample + 128x1152 GEMV per pixel -------------
__global__ __launch_bounds__(128) void k_deform(const bf16* __restrict__ h,
                                                const bf16* __restrict__ off,
                                                const float* __restrict__ dwt,
                                                const float* __restrict__ def_b,
                                                bf16* __restrict__ y){
    constexpr int DP = 8;                 // pixels per block (same row)
    __shared__ float s[DP * 1152];        // s[p][c*9+k]
    __shared__ float cw[DP * 9][4];
    __shared__ int   cyx[DP * 9][2];
    int t    = threadIdx.x;
    int pix0 = blockIdx.x * DP;
    int b    = pix0 / HW;
    int rem  = pix0 % HW;
    int yy   = rem / W;
    int x0   = rem % W;

    if (t < DP * 9){
        int p = t / 9, k = t % 9;
        float dy = b2f(off[(size_t)(pix0 + p) * 18 + 2 * k]);
        float dx = b2f(off[(size_t)(pix0 + p) * 18 + 2 * k + 1]);
        float py = yy + (k / 3 - 1) + dy;
        float px = (x0 + p) + (k % 3 - 1) + dx;
        float fy = floorf(py), fx = floorf(px);
        float wy = py - fy, wx = px - fx;
        cyx[t][0] = (int)fy; cyx[t][1] = (int)fx;
        cw[t][0] = (1 - wy) * (1 - wx);
        cw[t][1] = (1 - wy) * wx;
        cw[t][2] = wy * (1 - wx);
        cw[t][3] = wy * wx;
    }
    __syncthreads();

    {   // phase 1: c = t, gather bilinear samples (coalesced channel reads)
        int c = t;
        const bf16* hb = h + (size_t)b * HW * CO + c;
        for (int p = 0; p < DP; p++){
            for (int k = 0; k < 9; k++){
                int idx = p * 9 + k;
                int y0i = cyx[idx][0], x0i = cyx[idx][1];
                float w00 = cw[idx][0], w01 = cw[idx][1],
                      w10 = cw[idx][2], w11 = cw[idx][3];
                bool yv0 = (y0i >= 0     && y0i < H);
                bool yv1 = (y0i + 1 >= 0 && y0i + 1 < H);
                bool xv0 = (x0i >= 0     && x0i < W);
                bool xv1 = (x0i + 1 >= 0 && x0i + 1 < W);
                float v = 0.f;
                if (yv0 && xv0) v += w00 * b2f(hb[(size_t)(y0i * W + x0i) * CO]);
                if (yv0 && xv1) v += w01 * b2f(hb[(size_t)(y0i * W + x0i + 1) * CO]);
                if (yv1 && xv0) v += w10 * b2f(hb[(size_t)((y0i + 1) * W + x0i) * CO]);
                if (yv1 && xv1) v += w11 * b2f(hb[(size_t)((y0i + 1) * W + x0i + 1) * CO]);
                s[p * 1152 + c * 9 + k] = v;
            }
        }
    }
    __syncthreads();

    {   // phase 2: o = t, GEMV y[p][o] = sum_ck s[p][ck]*W[ck][o] + bias
        int o = t;
        float acc[DP];
        float bias = def_b[o];
#pragma unroll
        for (int p = 0; p < DP; p++) acc[p] = bias;
        for (int ck = 0; ck < 1152; ck += 4){
            float w0 = dwt[(ck + 0) * CO + o];
            float w1 = dwt[(ck + 1) * CO + o];
            float w2 = dwt[(ck + 2) * CO + o];
            float w3 = dwt[(ck + 3) * CO + o];
#pragma unroll
            for (int p = 0; p < DP; p++){
                const float4 sv = *(const float4*)&s[p * 1152 + ck];
                acc[p] += sv.x * w0 + sv.y * w1 + sv.z * w2 + sv.w * w3;
            }
        }
        bf16* yp = y + (size_t)pix0 * CO + o;
#pragma unroll
        for (int p = 0; p < DP; p++) yp[p * CO] = f2b(acc[p]);
    }
}

// ------------- BN2 apply + relu + NHWC->NCHW store (fp32 out) -------------
__global__ void k_final(const bf16* __restrict__ yb, const float* __restrict__ sc,
                        float* __restrict__ out){
    int i = blockIdx.x * blockDim.x + threadIdx.x;
    if (i >= NPIX * CO) return;
    int xw = i % W;
    int yh = (i / W) % H;
    int o  = (i / HW) % CO;
    int b  = i / (HW * CO);
    float v = b2f(yb[(size_t)(b * HW + yh * W + xw) * CO + o]);
    v = v * sc[o] + sc[128 + o];
    out[i] = v > 0.f ? v : 0.f;
}

extern "C" void kernel_launch(void* const* d_in, const int* in_sizes, int n_in,
                              void* d_out, int out_size, void* d_ws, size_t ws_size,
                              hipStream_t stream){
    // All reference tensors are jnp.float32 — read fp32, write fp32.
    const float* x      = (const float*)d_in[0];
    const float* skip   = (const float*)d_in[1];
    const float* conv1w = (const float*)d_in[2];
    const float* bn1g   = (const float*)d_in[3];
    const float* bn1b   = (const float*)d_in[4];
    const float* offw   = (const float*)d_in[5];
    const float* offb   = (const float*)d_in[6];
    const float* defw   = (const float*)d_in[7];
    const float* defb   = (const float*)d_in[8];
    const float* bn2g   = (const float*)d_in[9];
    const float* bn2b   = (const float*)d_in[10];
    float* out = (float*)d_out;

    char* ws = (char*)d_ws;
    size_t off_bytes = 0;
    auto alloc = [&](size_t bytes) -> void* {
        void* p = ws + off_bytes;
        off_bytes += (bytes + 255) & ~(size_t)255;
        return p;
    };
    bf16*  cat   = (bf16*) alloc((size_t)NPIX * CCAT * 2);   // 50.3 MB
    bf16*  c1    = (bf16*) alloc((size_t)NPIX * CO   * 2);   // 16.8 MB (becomes h)
    bf16*  offs  = (bf16*) alloc((size_t)NPIX * 18   * 2);   //  2.4 MB
    bf16*  yb    = (bf16*) alloc((size_t)NPIX * CO   * 2);   // 16.8 MB
    float* w1t   = (float*)alloc((size_t)9 * CCAT * CO * 4); //  1.8 MB
    float* offt  = (float*)alloc((size_t)9 * CO * 18 * 4);
    float* dwt   = (float*)alloc((size_t)CO * 9 * CO * 4);
    float* sums1 = (float*)alloc(256 * 4);
    float* sums2 = (float*)alloc(256 * 4);
    float* sc1   = (float*)alloc(256 * 4);
    float* sc2   = (float*)alloc(256 * 4);

    k_zero<<<1, 256, 0, stream>>>(sums1, 256);
    k_zero<<<1, 256, 0, stream>>>(sums2, 256);

    k_build_cat<<<(NPIX * CCAT + 255) / 256, 256, 0, stream>>>(x, skip, cat);
    k_tr_w1 <<<(9 * CCAT * CO + 255) / 256, 256, 0, stream>>>(conv1w, w1t);
    k_tr_off<<<(9 * CO * 18 + 255) / 256, 256, 0, stream>>>(offw, offt);
    k_tr_def<<<(CO * 9 * CO + 255) / 256, 256, 0, stream>>>(defw, dwt);

    k_conv1<<<NB * H * (W / 16), 128, 0, stream>>>(cat, w1t, c1);

    k_bn_stats<<<NPIX / 256, 256, 0, stream>>>(c1, sums1);
    k_bn_fin<<<1, 128, 0, stream>>>(sums1, bn1g, bn1b, sc1);
    k_bn_apply<<<(NPIX * CO + 255) / 256, 256, 0, stream>>>(c1, sc1);   // c1 -> h

    k_conv_off<<<NB * H, 128, 0, stream>>>(c1, offt, offb, offs);

    k_deform<<<NPIX / 8, 128, 0, stream>>>(c1, offs, dwt, defb, yb);

    k_bn_stats<<<NPIX / 256, 256, 0, stream>>>(yb, sums2);
    k_bn_fin<<<1, 128, 0, stream>>>(sums2, bn2g, bn2b, sc2);
    k_final<<<(NPIX * CO + 255) / 256, 256, 0, stream>>>(yb, sc2, out);
}

// Round 3
// 1468.978 us; speedup vs baseline: 4.1638x; 4.1638x over previous
//
#include <hip/hip_runtime.h>
#include <hip/hip_bf16.h>

typedef __hip_bfloat16 bf16;
typedef __bf16 bf16x8 __attribute__((ext_vector_type(8)));
typedef float  f32x4  __attribute__((ext_vector_type(4)));

constexpr int NB   = 4;
constexpr int H    = 128;
constexpr int W    = 128;
constexpr int HW   = H * W;
constexpr int NPIX = NB * HW;        // 65536
constexpr int CCAT = 384;
constexpr int CSKIP= 128;
constexpr int CIN  = 256;
constexpr int CO   = 128;
constexpr int HS   = 64;
constexpr int WP   = 130;            // padded H/W for cat
constexpr int K1   = 3456;           // conv1 GEMM K = 3*3*384
constexpr float EPS = 1e-5f;

__device__ __forceinline__ float b2f(bf16 v){ return __bfloat162float(v); }
__device__ __forceinline__ bf16  f2b(float v){ return __float2bfloat16(v); }

// async global->LDS, 16B per lane; LDS dst = wave-uniform base + lane*16
__device__ __forceinline__ void async_copy16(const void* g, void* s){
    __builtin_amdgcn_global_load_lds((const __attribute__((address_space(1))) void*)g,
                                     (__attribute__((address_space(3))) void*)s, 16, 0, 0);
}

// ---------------- zero helpers ----------------
__global__ void k_zero(float* p, int n){
    int i = blockIdx.x * blockDim.x + threadIdx.x;
    if (i < n) p[i] = 0.f;
}
__global__ void k_zero4(float4* p, int n4){
    int i = blockIdx.x * blockDim.x + threadIdx.x;
    int stride = gridDim.x * blockDim.x;
    for (; i < n4; i += stride) p[i] = make_float4(0.f, 0.f, 0.f, 0.f);
}

// ------------- build cat_pad[b][y+1][x+1][c] = [skip ; upsample2x(x)], bf16 -------------
__global__ void k_build_cat(const float* __restrict__ x, const float* __restrict__ skip,
                            bf16* __restrict__ catp){
    int i = blockIdx.x * blockDim.x + threadIdx.x;
    if (i >= NPIX * CCAT) return;
    int c   = i % CCAT;
    int pix = i / CCAT;
    int xx  = pix % W;
    int yy  = (pix / W) % H;
    int b   = pix / HW;
    float v;
    if (c < CSKIP) {
        v = skip[((b * CSKIP + c) * H + yy) * W + xx];
    } else {
        int ic = c - CSKIP;
        float cy = (yy * 63.0f) / 127.0f;
        float cx = (xx * 63.0f) / 127.0f;
        int y0 = (int)cy, x0 = (int)cx;
        int y1 = min(y0 + 1, HS - 1), x1 = min(x0 + 1, HS - 1);
        float wy = cy - y0, wx = cx - x0;
        const float* xb = x + ((size_t)(b * CIN + ic) * HS) * HS;
        float v00 = xb[y0 * HS + x0];
        float v01 = xb[y0 * HS + x1];
        float v10 = xb[y1 * HS + x0];
        float v11 = xb[y1 * HS + x1];
        v = v00 * (1 - wy) * (1 - wx) + v01 * (1 - wy) * wx
          + v10 * wy * (1 - wx)       + v11 * wy * wx;
    }
    catp[(((size_t)b * WP + yy + 1) * WP + xx + 1) * CCAT + c] = f2b(v);
}

// ------------- weight transposes -------------
// conv1 weights: OIHW fp32 -> bf16 [oc][ky*1152 + kx*384 + ic]
__global__ void k_tr_w1b(const float* __restrict__ w, bf16* __restrict__ wt){
    int i = blockIdx.x * blockDim.x + threadIdx.x;
    if (i >= CO * K1) return;
    int k  = i % K1;
    int oc = i / K1;
    int ky = k / 1152; int r = k % 1152; int kx = r / 384; int ic = r % 384;
    wt[i] = f2b(w[((oc * CCAT + ic) * 3 + ky) * 3 + kx]);
}
__global__ void k_tr_off(const float* __restrict__ w, float* __restrict__ wt){
    int i = blockIdx.x * blockDim.x + threadIdx.x;
    if (i >= 9 * CO * 18) return;
    int oc = i % 18; int r = i / 18; int ic = r % CO; int kk = r / CO;
    wt[i] = w[(oc * CO + ic) * 9 + kk];
}
__global__ void k_tr_def(const float* __restrict__ w, float* __restrict__ wt){
    int i = blockIdx.x * blockDim.x + threadIdx.x;
    if (i >= CO * 9 * CO) return;
    int o = i % CO; int r = i / CO;      // r = c*9+k
    int c = r / 9,  k = r % 9;
    wt[i] = w[(o * CO + c) * 9 + k];
}

// ------------- conv1 as implicit-GEMM MFMA -------------
// Block: 256 thr (4 waves), tile = 128 pixels (one image row) x 128 oc, K=3456.
// A: cat_pad row window (contiguous per K-chunk in NHWC). B: wbt[oc][k] bf16.
// LDS layout: [row][oct] with oct ^= (row&7) swizzle -> 2-way read conflicts (free).
__global__ __launch_bounds__(256) void k_conv1_mfma(const bf16* __restrict__ catp,
                                                    const bf16* __restrict__ wbt,
                                                    bf16* __restrict__ c1){
    __shared__ unsigned short Ab[128 * 64];
    __shared__ unsigned short Bb[128 * 64];
    int t = threadIdx.x;
    int l = t & 63, w = t >> 6;
    int y = blockIdx.x % H, b = blockIdx.x / H;

    int pr   = l >> 3;               // lane's row-within-issue (0..7)
    int koct = (l & 7) ^ pr;         // swizzled oct this lane fetches
    int m    = l & 15, quad = l >> 4;
    int wm   = w & 1,  wn   = w >> 1;

    f32x4 acc[4][4];
#pragma unroll
    for (int i = 0; i < 4; i++)
#pragma unroll
        for (int j = 0; j < 4; j++) acc[i][j] = f32x4{0.f, 0.f, 0.f, 0.f};

    const size_t rowStride = (size_t)WP * CCAT;
    for (int ky = 0; ky < 3; ky++){
        const bf16* Arow = catp + ((size_t)(b * WP) + y + ky) * rowStride;
        for (int kc = 0; kc < 18; kc++){
            int c0 = kc / 6, r0 = (kc % 6) * 64;   // k-chunk never straddles a column
            __syncthreads();
#pragma unroll
            for (int i = 0; i < 4; i++){           // A: 8 pixels per issue
                int px = w * 32 + i * 8 + pr;
                async_copy16(Arow + (size_t)(px + c0) * CCAT + r0 + koct * 8,
                             &Ab[(w * 32 + i * 8) * 64]);
            }
            int kg = ky * 1152 + kc * 64;
#pragma unroll
            for (int i = 0; i < 4; i++){           // B: 8 ocs per issue
                int oc = w * 32 + i * 8 + pr;
                async_copy16(wbt + (size_t)oc * K1 + kg + koct * 8,
                             &Bb[(w * 32 + i * 8) * 64]);
            }
            __syncthreads();
            const bf16x8* ap = (const bf16x8*)Ab;
            const bf16x8* bp = (const bf16x8*)Bb;
#pragma unroll
            for (int ks = 0; ks < 2; ks++){
                bf16x8 af[4], bfr[4];
#pragma unroll
                for (int mi = 0; mi < 4; mi++){
                    int px = wm * 64 + mi * 16 + m;
                    af[mi] = ap[px * 8 + ((ks * 4 + quad) ^ (px & 7))];
                }
#pragma unroll
                for (int ni = 0; ni < 4; ni++){
                    int oc = wn * 64 + ni * 16 + m;
                    bfr[ni] = bp[oc * 8 + ((ks * 4 + quad) ^ (oc & 7))];
                }
#pragma unroll
                for (int mi = 0; mi < 4; mi++)
#pragma unroll
                    for (int ni = 0; ni < 4; ni++)
                        acc[mi][ni] = __builtin_amdgcn_mfma_f32_16x16x32_bf16(
                            af[mi], bfr[ni], acc[mi][ni], 0, 0, 0);
            }
        }
    }
    // epilogue: C/D layout col=lane&15, row=quad*4+reg
    size_t obase = ((size_t)b * HW + (size_t)y * W) * CO;
#pragma unroll
    for (int mi = 0; mi < 4; mi++){
        int p0 = wm * 64 + mi * 16 + quad * 4;
#pragma unroll
        for (int ni = 0; ni < 4; ni++){
            int oc = wn * 64 + ni * 16 + m;
#pragma unroll
            for (int r = 0; r < 4; r++)
                c1[obase + (size_t)(p0 + r) * CO + oc] = f2b(acc[mi][ni][r]);
        }
    }
}

// ------------- BN stats: per-channel sum & sumsq over NHWC [NPIX,128] -------------
__global__ __launch_bounds__(256) void k_bn_stats(const bf16* __restrict__ t,
                                                  float* __restrict__ sums){
    int c    = threadIdx.x & 127;
    int half = threadIdx.x >> 7;
    int pix0 = blockIdx.x * 256;
    float s = 0.f, q = 0.f;
    for (int p = half; p < 256; p += 2){
        float v = b2f(t[(size_t)(pix0 + p) * CO + c]);
        s += v; q += v * v;
    }
    __shared__ float ls[256], lq[256];
    ls[threadIdx.x] = s; lq[threadIdx.x] = q;
    __syncthreads();
    if (threadIdx.x < 128){
        atomicAdd(&sums[c],       ls[threadIdx.x] + ls[threadIdx.x + 128]);
        atomicAdd(&sums[128 + c], lq[threadIdx.x] + lq[threadIdx.x + 128]);
    }
}

__global__ void k_bn_fin(const float* __restrict__ sums, const float* __restrict__ g,
                         const float* __restrict__ bb, float* __restrict__ sc){
    int c = threadIdx.x;
    if (c >= CO) return;
    float n    = (float)NPIX;
    float mean = sums[c] / n;
    float var  = sums[128 + c] / n - mean * mean;
    float scale = g[c] * rsqrtf(var + EPS);
    sc[c]       = scale;
    sc[128 + c] = bb[c] - mean * scale;
}

__global__ void k_bn_apply(bf16* __restrict__ t, const float* __restrict__ sc){
    int i = blockIdx.x * blockDim.x + threadIdx.x;
    if (i >= NPIX * CO) return;
    int c = i & 127;
    float v = b2f(t[i]) * sc[c] + sc[128 + c];
    t[i] = f2b(v > 0.f ? v : 0.f);
}

// ------------- offset conv: h(NHWC,128) -> off(NHWC,18) -------------
__global__ __launch_bounds__(128) void k_conv_off(const bf16* __restrict__ h,
                                                  const float* __restrict__ wt,
                                                  const float* __restrict__ off_b,
                                                  bf16* __restrict__ off){
    int x  = threadIdx.x;
    int yy = blockIdx.x % H;
    int b  = blockIdx.x / H;
    float acc[18];
#pragma unroll
    for (int o = 0; o < 18; o++) acc[o] = off_b[o];
    for (int ky = 0; ky < 3; ky++){
        int row = yy + ky - 1;
        if (row < 0 || row >= H) continue;
        const bf16* hr = h + (size_t)(b * HW + row * W) * CO;
        for (int ic = 0; ic < CO; ic++){
            float in0 = (x - 1 >= 0) ? b2f(hr[(x - 1) * CO + ic]) : 0.f;
            float in1 = b2f(hr[x * CO + ic]);
            float in2 = (x + 1 < W)  ? b2f(hr[(x + 1) * CO + ic]) : 0.f;
            const float* wp = wt + ((ky * 3 + 0) * CO + ic) * 18;
#pragma unroll
            for (int o = 0; o < 18; o++) acc[o] += in0 * wp[o];
            wp += CO * 18;
#pragma unroll
            for (int o = 0; o < 18; o++) acc[o] += in1 * wp[o];
            wp += CO * 18;
#pragma unroll
            for (int o = 0; o < 18; o++) acc[o] += in2 * wp[o];
        }
    }
    bf16* op = off + (size_t)(b * HW + yy * W + x) * 18;
#pragma unroll
    for (int o = 0; o < 18; o++) op[o] = f2b(acc[o]);
}

// ------------- deform sample + 128x1152 GEMV per pixel -------------
__global__ __launch_bounds__(128) void k_deform(const bf16* __restrict__ h,
                                                const bf16* __restrict__ off,
                                                const float* __restrict__ dwt,
                                                const float* __restrict__ def_b,
                                                bf16* __restrict__ y){
    constexpr int DP = 8;
    __shared__ float s[DP * 1152];
    __shared__ float cw[DP * 9][4];
    __shared__ int   cyx[DP * 9][2];
    int t    = threadIdx.x;
    int pix0 = blockIdx.x * DP;
    int b    = pix0 / HW;
    int rem  = pix0 % HW;
    int yy   = rem / W;
    int x0   = rem % W;

    if (t < DP * 9){
        int p = t / 9, k = t % 9;
        float dy = b2f(off[(size_t)(pix0 + p) * 18 + 2 * k]);
        float dx = b2f(off[(size_t)(pix0 + p) * 18 + 2 * k + 1]);
        float py = yy + (k / 3 - 1) + dy;
        float px = (x0 + p) + (k % 3 - 1) + dx;
        float fy = floorf(py), fx = floorf(px);
        float wy = py - fy, wx = px - fx;
        cyx[t][0] = (int)fy; cyx[t][1] = (int)fx;
        cw[t][0] = (1 - wy) * (1 - wx);
        cw[t][1] = (1 - wy) * wx;
        cw[t][2] = wy * (1 - wx);
        cw[t][3] = wy * wx;
    }
    __syncthreads();

    {   // phase 1: c = t, gather bilinear samples
        int c = t;
        const bf16* hb = h + (size_t)b * HW * CO + c;
        for (int p = 0; p < DP; p++){
            for (int k = 0; k < 9; k++){
                int idx = p * 9 + k;
                int y0i = cyx[idx][0], x0i = cyx[idx][1];
                float w00 = cw[idx][0], w01 = cw[idx][1],
                      w10 = cw[idx][2], w11 = cw[idx][3];
                bool yv0 = (y0i >= 0     && y0i < H);
                bool yv1 = (y0i + 1 >= 0 && y0i + 1 < H);
                bool xv0 = (x0i >= 0     && x0i < W);
                bool xv1 = (x0i + 1 >= 0 && x0i + 1 < W);
                float v = 0.f;
                if (yv0 && xv0) v += w00 * b2f(hb[(size_t)(y0i * W + x0i) * CO]);
                if (yv0 && xv1) v += w01 * b2f(hb[(size_t)(y0i * W + x0i + 1) * CO]);
                if (yv1 && xv0) v += w10 * b2f(hb[(size_t)((y0i + 1) * W + x0i) * CO]);
                if (yv1 && xv1) v += w11 * b2f(hb[(size_t)((y0i + 1) * W + x0i + 1) * CO]);
                s[p * 1152 + c * 9 + k] = v;
            }
        }
    }
    __syncthreads();

    {   // phase 2: o = t, GEMV
        int o = t;
        float acc[DP];
        float bias = def_b[o];
#pragma unroll
        for (int p = 0; p < DP; p++) acc[p] = bias;
        for (int ck = 0; ck < 1152; ck += 4){
            float w0 = dwt[(ck + 0) * CO + o];
            float w1 = dwt[(ck + 1) * CO + o];
            float w2 = dwt[(ck + 2) * CO + o];
            float w3 = dwt[(ck + 3) * CO + o];
#pragma unroll
            for (int p = 0; p < DP; p++){
                const float4 sv = *(const float4*)&s[p * 1152 + ck];
                acc[p] += sv.x * w0 + sv.y * w1 + sv.z * w2 + sv.w * w3;
            }
        }
        bf16* yp = y + (size_t)pix0 * CO + o;
#pragma unroll
        for (int p = 0; p < DP; p++) yp[p * CO] = f2b(acc[p]);
    }
}

// ------------- BN2 apply + relu + NHWC->NCHW store (fp32 out) -------------
__global__ void k_final(const bf16* __restrict__ yb, const float* __restrict__ sc,
                        float* __restrict__ out){
    int i = blockIdx.x * blockDim.x + threadIdx.x;
    if (i >= NPIX * CO) return;
    int xw = i % W;
    int yh = (i / W) % H;
    int o  = (i / HW) % CO;
    int b  = i / (HW * CO);
    float v = b2f(yb[(size_t)(b * HW + yh * W + xw) * CO + o]);
    v = v * sc[o] + sc[128 + o];
    out[i] = v > 0.f ? v : 0.f;
}

extern "C" void kernel_launch(void* const* d_in, const int* in_sizes, int n_in,
                              void* d_out, int out_size, void* d_ws, size_t ws_size,
                              hipStream_t stream){
    const float* x      = (const float*)d_in[0];
    const float* skip   = (const float*)d_in[1];
    const float* conv1w = (const float*)d_in[2];
    const float* bn1g   = (const float*)d_in[3];
    const float* bn1b   = (const float*)d_in[4];
    const float* offw   = (const float*)d_in[5];
    const float* offb   = (const float*)d_in[6];
    const float* defw   = (const float*)d_in[7];
    const float* defb   = (const float*)d_in[8];
    const float* bn2g   = (const float*)d_in[9];
    const float* bn2b   = (const float*)d_in[10];
    float* out = (float*)d_out;

    char* ws = (char*)d_ws;
    size_t off_bytes = 0;
    auto alloc = [&](size_t bytes) -> void* {
        void* p = ws + off_bytes;
        off_bytes += (bytes + 255) & ~(size_t)255;
        return p;
    };
    const size_t catp_elems = (size_t)NB * WP * WP * CCAT;       // padded cat
    bf16*  catp  = (bf16*) alloc(catp_elems * 2);                // 51.9 MB
    bf16*  c1    = (bf16*) alloc((size_t)NPIX * CO * 2);         // 16.8 MB (becomes h)
    bf16*  offs  = (bf16*) alloc((size_t)NPIX * 18 * 2);
    bf16*  yb    = (bf16*) alloc((size_t)NPIX * CO * 2);
    bf16*  wbt   = (bf16*) alloc((size_t)CO * K1 * 2);           // conv1 W^T bf16
    float* offt  = (float*)alloc((size_t)9 * CO * 18 * 4);
    float* dwt   = (float*)alloc((size_t)CO * 9 * CO * 4);
    float* sums1 = (float*)alloc(256 * 4);
    float* sums2 = (float*)alloc(256 * 4);
    float* sc1   = (float*)alloc(256 * 4);
    float* sc2   = (float*)alloc(256 * 4);

    k_zero<<<1, 256, 0, stream>>>(sums1, 256);
    k_zero<<<1, 256, 0, stream>>>(sums2, 256);
    k_zero4<<<2048, 256, 0, stream>>>((float4*)catp, (int)(catp_elems * 2 / 16));

    k_build_cat<<<(NPIX * CCAT + 255) / 256, 256, 0, stream>>>(x, skip, catp);
    k_tr_w1b<<<(CO * K1 + 255) / 256, 256, 0, stream>>>(conv1w, wbt);
    k_tr_off<<<(9 * CO * 18 + 255) / 256, 256, 0, stream>>>(offw, offt);
    k_tr_def<<<(CO * 9 * CO + 255) / 256, 256, 0, stream>>>(defw, dwt);

    k_conv1_mfma<<<NB * H, 256, 0, stream>>>(catp, wbt, c1);

    k_bn_stats<<<NPIX / 256, 256, 0, stream>>>(c1, sums1);
    k_bn_fin<<<1, 128, 0, stream>>>(sums1, bn1g, bn1b, sc1);
    k_bn_apply<<<(NPIX * CO + 255) / 256, 256, 0, stream>>>(c1, sc1);   // c1 -> h

    k_conv_off<<<NB * H, 128, 0, stream>>>(c1, offt, offb, offs);

    k_deform<<<NPIX / 8, 128, 0, stream>>>(c1, offs, dwt, defb, yb);

    k_bn_stats<<<NPIX / 256, 256, 0, stream>>>(yb, sums2);
    k_bn_fin<<<1, 128, 0, stream>>>(sums2, bn2g, bn2b, sc2);
    k_final<<<(NPIX * CO + 255) / 256, 256, 0, stream>>>(yb, sc2, out);
}

// Round 4
// 558.440 us; speedup vs baseline: 10.9529x; 2.6305x over previous
//
#include <hip/hip_runtime.h>
#include <hip/hip_bf16.h>

typedef __hip_bfloat16 bf16;
typedef __bf16 bf16x8 __attribute__((ext_vector_type(8)));
typedef __bf16 bf16x4 __attribute__((ext_vector_type(4)));
typedef float  f32x4  __attribute__((ext_vector_type(4)));

constexpr int NB   = 4;
constexpr int H    = 128;
constexpr int W    = 128;
constexpr int HW   = H * W;
constexpr int NPIX = NB * HW;        // 65536
constexpr int CCAT = 384;
constexpr int CSKIP= 128;
constexpr int CIN  = 256;
constexpr int CO   = 128;
constexpr int HS   = 64;
constexpr int WP   = 130;            // padded H/W
constexpr int K1   = 3456;           // conv1 GEMM K
constexpr int KD   = 1152;           // deform/off GEMM K
constexpr float EPS = 1e-5f;

__device__ __forceinline__ float b2f(bf16 v){ return __bfloat162float(v); }
__device__ __forceinline__ bf16  f2b(float v){ return __float2bfloat16(v); }

__device__ __forceinline__ void async_copy16(const void* g, void* s){
    __builtin_amdgcn_global_load_lds((const __attribute__((address_space(1))) void*)g,
                                     (__attribute__((address_space(3))) void*)s, 16, 0, 0);
}

// ---------------- zero helpers ----------------
__global__ void k_zero(float* p, int n){
    int i = blockIdx.x * blockDim.x + threadIdx.x;
    if (i < n) p[i] = 0.f;
}
__global__ void k_zero4(float4* p, int n4){
    int i = blockIdx.x * blockDim.x + threadIdx.x;
    int stride = gridDim.x * blockDim.x;
    for (; i < n4; i += stride) p[i] = make_float4(0.f, 0.f, 0.f, 0.f);
}

// ------------- build cat_pad[b][y+1][x+1][c], bf16 -------------
__global__ void k_build_cat(const float* __restrict__ x, const float* __restrict__ skip,
                            bf16* __restrict__ catp){
    int i = blockIdx.x * blockDim.x + threadIdx.x;
    if (i >= NPIX * CCAT) return;
    int c   = i % CCAT;
    int pix = i / CCAT;
    int xx  = pix % W;
    int yy  = (pix / W) % H;
    int b   = pix / HW;
    float v;
    if (c < CSKIP) {
        v = skip[((b * CSKIP + c) * H + yy) * W + xx];
    } else {
        int ic = c - CSKIP;
        float cy = (yy * 63.0f) / 127.0f;
        float cx = (xx * 63.0f) / 127.0f;
        int y0 = (int)cy, x0 = (int)cx;
        int y1 = min(y0 + 1, HS - 1), x1 = min(x0 + 1, HS - 1);
        float wy = cy - y0, wx = cx - x0;
        const float* xb = x + ((size_t)(b * CIN + ic) * HS) * HS;
        float v00 = xb[y0 * HS + x0];
        float v01 = xb[y0 * HS + x1];
        float v10 = xb[y1 * HS + x0];
        float v11 = xb[y1 * HS + x1];
        v = v00 * (1 - wy) * (1 - wx) + v01 * (1 - wy) * wx
          + v10 * wy * (1 - wx)       + v11 * wy * wx;
    }
    catp[(((size_t)b * WP + yy + 1) * WP + xx + 1) * CCAT + c] = f2b(v);
}

// ------------- weight transposes -------------
__global__ void k_tr_w1b(const float* __restrict__ w, bf16* __restrict__ wt){
    int i = blockIdx.x * blockDim.x + threadIdx.x;
    if (i >= CO * K1) return;
    int k  = i % K1;
    int oc = i / K1;
    int ky = k / 1152; int r = k % 1152; int kx = r / 384; int ic = r % 384;
    wt[i] = f2b(w[((oc * CCAT + ic) * 3 + ky) * 3 + kx]);
}
// offset conv: [32 oc][kk = ky*384 + kx*128 + ic], rows >=18 zero
__global__ void k_tr_offb(const float* __restrict__ w, bf16* __restrict__ wt){
    int i = blockIdx.x * blockDim.x + threadIdx.x;
    if (i >= 32 * KD) return;
    int kk = i % KD, o = i / KD;
    int ky = kk / 384; int r = kk % 384; int kx = r >> 7; int ic = r & 127;
    wt[i] = (o < 18) ? f2b(w[((o * CO + ic) * 3 + ky) * 3 + kx]) : f2b(0.f);
}
// deform: [128 oc][kk = kp*128 + c]
__global__ void k_tr_defb(const float* __restrict__ w, bf16* __restrict__ wt){
    int i = blockIdx.x * blockDim.x + threadIdx.x;
    if (i >= CO * KD) return;
    int kk = i % KD, o = i / KD;
    int kp = kk >> 7, c = kk & 127;
    wt[i] = f2b(w[(o * CO + c) * 9 + kp]);
}

// ------------- conv1 implicit-GEMM MFMA: catp -> hp (padded, pre-BN) -------------
__global__ __launch_bounds__(256) void k_conv1_mfma(const bf16* __restrict__ catp,
                                                    const bf16* __restrict__ wbt,
                                                    bf16* __restrict__ hp){
    __shared__ unsigned short Ab[128 * 64];
    __shared__ unsigned short Bb[128 * 64];
    int t = threadIdx.x;
    int l = t & 63, w = t >> 6;
    int y = blockIdx.x % H, b = blockIdx.x / H;

    int pr   = l >> 3;
    int koct = (l & 7) ^ pr;
    int m    = l & 15, quad = l >> 4;
    int wm   = w & 1,  wn   = w >> 1;

    f32x4 acc[4][4];
#pragma unroll
    for (int i = 0; i < 4; i++)
#pragma unroll
        for (int j = 0; j < 4; j++) acc[i][j] = f32x4{0.f, 0.f, 0.f, 0.f};

    const size_t rowStride = (size_t)WP * CCAT;
    for (int ky = 0; ky < 3; ky++){
        const bf16* Arow = catp + ((size_t)(b * WP) + y + ky) * rowStride;
        for (int kc = 0; kc < 18; kc++){
            int c0 = kc / 6, r0 = (kc % 6) * 64;
            __syncthreads();
#pragma unroll
            for (int i = 0; i < 4; i++){
                int px = w * 32 + i * 8 + pr;
                async_copy16(Arow + (size_t)(px + c0) * CCAT + r0 + koct * 8,
                             &Ab[(w * 32 + i * 8) * 64]);
            }
            int kg = ky * 1152 + kc * 64;
#pragma unroll
            for (int i = 0; i < 4; i++){
                int oc = w * 32 + i * 8 + pr;
                async_copy16(wbt + (size_t)oc * K1 + kg + koct * 8,
                             &Bb[(w * 32 + i * 8) * 64]);
            }
            __syncthreads();
            const bf16x8* ap = (const bf16x8*)Ab;
            const bf16x8* bp = (const bf16x8*)Bb;
#pragma unroll
            for (int ks = 0; ks < 2; ks++){
                bf16x8 af[4], bfr[4];
#pragma unroll
                for (int mi = 0; mi < 4; mi++){
                    int px = wm * 64 + mi * 16 + m;
                    af[mi] = ap[px * 8 + ((ks * 4 + quad) ^ (px & 7))];
                }
#pragma unroll
                for (int ni = 0; ni < 4; ni++){
                    int oc = wn * 64 + ni * 16 + m;
                    bfr[ni] = bp[oc * 8 + ((ks * 4 + quad) ^ (oc & 7))];
                }
#pragma unroll
                for (int mi = 0; mi < 4; mi++)
#pragma unroll
                    for (int ni = 0; ni < 4; ni++)
                        acc[mi][ni] = __builtin_amdgcn_mfma_f32_16x16x32_bf16(
                            af[mi], bfr[ni], acc[mi][ni], 0, 0, 0);
            }
        }
    }
    // write padded interior
    size_t obase = (((size_t)b * WP + y + 1) * WP + 1) * CO;
#pragma unroll
    for (int mi = 0; mi < 4; mi++){
        int p0 = wm * 64 + mi * 16 + quad * 4;
#pragma unroll
        for (int ni = 0; ni < 4; ni++){
            int oc = wn * 64 + ni * 16 + m;
#pragma unroll
            for (int r = 0; r < 4; r++)
                hp[obase + (size_t)(p0 + r) * CO + oc] = f2b(acc[mi][ni][r]);
        }
    }
}

// ------------- BN stats over padded hp interior -------------
__global__ __launch_bounds__(256) void k_bn_stats_pad(const bf16* __restrict__ t,
                                                      float* __restrict__ sums){
    int c    = threadIdx.x & 127;
    int half = threadIdx.x >> 7;
    int pix0 = blockIdx.x * 256;
    float s = 0.f, q = 0.f;
    for (int p = half; p < 256; p += 2){
        int pix = pix0 + p;
        int xw = pix & 127, yh = (pix >> 7) & 127, b = pix >> 14;
        float v = b2f(t[(((size_t)b * WP + yh + 1) * WP + xw + 1) * CO + c]);
        s += v; q += v * v;
    }
    __shared__ float ls[256], lq[256];
    ls[threadIdx.x] = s; lq[threadIdx.x] = q;
    __syncthreads();
    if (threadIdx.x < 128){
        atomicAdd(&sums[c],       ls[threadIdx.x] + ls[threadIdx.x + 128]);
        atomicAdd(&sums[128 + c], lq[threadIdx.x] + lq[threadIdx.x + 128]);
    }
}
// plain NHWC version (yb)
__global__ __launch_bounds__(256) void k_bn_stats(const bf16* __restrict__ t,
                                                  float* __restrict__ sums){
    int c    = threadIdx.x & 127;
    int half = threadIdx.x >> 7;
    int pix0 = blockIdx.x * 256;
    float s = 0.f, q = 0.f;
    for (int p = half; p < 256; p += 2){
        float v = b2f(t[(size_t)(pix0 + p) * CO + c]);
        s += v; q += v * v;
    }
    __shared__ float ls[256], lq[256];
    ls[threadIdx.x] = s; lq[threadIdx.x] = q;
    __syncthreads();
    if (threadIdx.x < 128){
        atomicAdd(&sums[c],       ls[threadIdx.x] + ls[threadIdx.x + 128]);
        atomicAdd(&sums[128 + c], lq[threadIdx.x] + lq[threadIdx.x + 128]);
    }
}

__global__ void k_bn_fin(const float* __restrict__ sums, const float* __restrict__ g,
                         const float* __restrict__ bb, float* __restrict__ sc){
    int c = threadIdx.x;
    if (c >= CO) return;
    float n    = (float)NPIX;
    float mean = sums[c] / n;
    float var  = sums[128 + c] / n - mean * mean;
    float scale = g[c] * rsqrtf(var + EPS);
    sc[c]       = scale;
    sc[128 + c] = bb[c] - mean * scale;
}

// affine+relu in place on padded hp interior
__global__ void k_bn_apply_pad(bf16* __restrict__ t, const float* __restrict__ sc){
    int i = blockIdx.x * blockDim.x + threadIdx.x;
    if (i >= NPIX * CO) return;
    int c = i & 127;
    int pix = i >> 7;
    int xw = pix & 127, yh = (pix >> 7) & 127, b = pix >> 14;
    size_t a = (((size_t)b * WP + yh + 1) * WP + xw + 1) * CO + c;
    float v = b2f(t[a]) * sc[c] + sc[128 + c];
    t[a] = f2b(v > 0.f ? v : 0.f);
}

// ------------- offset conv as MFMA: hp -> offs[pix][18] -------------
__global__ __launch_bounds__(256) void k_conv_off_mfma(const bf16* __restrict__ hp,
                                                       const bf16* __restrict__ wob,
                                                       const float* __restrict__ off_b,
                                                       bf16* __restrict__ offs){
    __shared__ unsigned short Ab[128 * 64];
    __shared__ unsigned short Bb[32 * 64];
    int t = threadIdx.x, l = t & 63, w = t >> 6;
    int y = blockIdx.x % H, b = blockIdx.x / H;
    int pr = l >> 3, koct = (l & 7) ^ pr;
    int m = l & 15, quad = l >> 4;
    int wm = w & 1, wn = w >> 1;

    f32x4 acc[4];
#pragma unroll
    for (int i = 0; i < 4; i++) acc[i] = f32x4{0.f, 0.f, 0.f, 0.f};

    const size_t rowStride = (size_t)WP * CO;
    for (int ky = 0; ky < 3; ky++){
        const bf16* Arow = hp + ((size_t)(b * WP) + y + ky) * rowStride;
        for (int kc = 0; kc < 6; kc++){
            int kx = kc >> 1, r0 = (kc & 1) * 64;
            __syncthreads();
#pragma unroll
            for (int i = 0; i < 4; i++){
                int px = w * 32 + i * 8 + pr;
                async_copy16(Arow + (size_t)(px + kx) * CO + r0 + koct * 8,
                             &Ab[(w * 32 + i * 8) * 64]);
            }
            int kg = ky * 384 + kx * 128 + r0;
            async_copy16(wob + (size_t)(w * 8 + pr) * KD + kg + koct * 8,
                         &Bb[(w * 8) * 64]);
            __syncthreads();
            const bf16x8* ap = (const bf16x8*)Ab;
            const bf16x8* bp = (const bf16x8*)Bb;
#pragma unroll
            for (int ks = 0; ks < 2; ks++){
                int oc = wn * 16 + m;
                bf16x8 bfr = bp[oc * 8 + ((ks * 4 + quad) ^ (oc & 7))];
#pragma unroll
                for (int mi = 0; mi < 4; mi++){
                    int px = wm * 64 + mi * 16 + m;
                    bf16x8 af = ap[px * 8 + ((ks * 4 + quad) ^ (px & 7))];
                    acc[mi] = __builtin_amdgcn_mfma_f32_16x16x32_bf16(af, bfr, acc[mi], 0, 0, 0);
                }
            }
        }
    }
    int oc = wn * 16 + m;
    if (oc < 18){
        float bias = off_b[oc];
        int rowpix = b * HW + y * W;
#pragma unroll
        for (int mi = 0; mi < 4; mi++){
            int p0 = wm * 64 + mi * 16 + quad * 4;
#pragma unroll
            for (int r = 0; r < 4; r++)
                offs[(size_t)(rowpix + p0 + r) * 18 + oc] = f2b(acc[mi][r] + bias);
        }
    }
}

// ------------- deform: generate sampled A in LDS + MFMA GEMM -------------
__global__ __launch_bounds__(256) void k_deform_mfma(const bf16* __restrict__ hp,
                                                     const bf16* __restrict__ offs,
                                                     const bf16* __restrict__ wdb,
                                                     const float* __restrict__ def_b,
                                                     bf16* __restrict__ y){
    __shared__ unsigned short Ab[128 * 64];
    __shared__ unsigned short Bb[128 * 64];
    __shared__ int2   sc_yx[9 * 128];
    __shared__ float4 sc_w[9 * 128];

    int t = threadIdx.x, l = t & 63, w = t >> 6;
    int yrow = blockIdx.x % H, b = blockIdx.x / H;
    int rowpix = b * HW + yrow * W;

    // precompute clamped corner offsets + pre-masked weights for 9 pts x 128 px
    for (int idx = t; idx < 9 * 128; idx += 256){
        int kp = idx >> 7, px = idx & 127;
        float dy = b2f(offs[(size_t)(rowpix + px) * 18 + 2 * kp]);
        float dx = b2f(offs[(size_t)(rowpix + px) * 18 + 2 * kp + 1]);
        float py = yrow + (kp / 3 - 1) + dy;
        float pxx = px + (kp % 3 - 1) + dx;
        float fy = floorf(py), fx = floorf(pxx);
        float wy = py - fy, wx = pxx - fx;
        int y0 = (int)fy, x0 = (int)fx;
        bool vy0 = (y0 >= 0) && (y0 < H);
        bool vy1 = (y0 + 1 >= 0) && (y0 + 1 < H);
        bool vx0 = (x0 >= 0) && (x0 < W);
        bool vx1 = (x0 + 1 >= 0) && (x0 + 1 < W);
        int y0c = min(max(y0, 0), H - 1),     y1c = min(max(y0 + 1, 0), H - 1);
        int x0c = min(max(x0, 0), W - 1),     x1c = min(max(x0 + 1, 0), W - 1);
        sc_yx[idx] = make_int2(((y0c + 1) * WP) | (((y1c + 1) * WP) << 16),
                               (x0c + 1) | ((x1c + 1) << 16));
        sc_w[idx] = make_float4((1 - wy) * (1 - wx) * (float)(vy0 && vx0),
                                (1 - wy) * wx       * (float)(vy0 && vx1),
                                wy * (1 - wx)       * (float)(vy1 && vx0),
                                wy * wx             * (float)(vy1 && vx1));
    }
    __syncthreads();

    int pr = l >> 3, koct = (l & 7) ^ pr;
    int m = l & 15, quad = l >> 4;
    int wm = w & 1, wn = w >> 1;
    int g = l >> 4, j = l & 15;          // A-gen mapping

    f32x4 acc[4][4];
#pragma unroll
    for (int i = 0; i < 4; i++)
#pragma unroll
        for (int jj = 0; jj < 4; jj++) acc[i][jj] = f32x4{0.f, 0.f, 0.f, 0.f};

    const bf16* hpb = hp + (size_t)b * WP * WP * CO;

    for (int kc = 0; kc < 18; kc++){
        int kp = kc >> 1, ch = (kc & 1) * 64;
        __syncthreads();
        // B staging (async)
        int kg = kp * 128 + ch;
#pragma unroll
        for (int i = 0; i < 4; i++){
            int oc = w * 32 + i * 8 + pr;
            async_copy16(wdb + (size_t)oc * KD + kg + koct * 8,
                         &Bb[(w * 32 + i * 8) * 64]);
        }
        // A generation: bilinear gather, 4 channels/lane, 8 px/lane-group
        int cb = ch + j * 4;
#pragma unroll
        for (int p = 0; p < 8; p++){
            int px = w * 32 + g * 8 + p;
            int idx = kp * 128 + px;
            int2 yx = sc_yx[idx];
            float4 w4 = sc_w[idx];
            int r0 = yx.x & 0xffff, r1 = ((unsigned)yx.x) >> 16;
            int c0 = yx.y & 0xffff, c1 = ((unsigned)yx.y) >> 16;
            const bf16* base = hpb + cb;
            bf16x4 s00 = *(const bf16x4*)(base + (size_t)(r0 + c0) * CO);
            bf16x4 s01 = *(const bf16x4*)(base + (size_t)(r0 + c1) * CO);
            bf16x4 s10 = *(const bf16x4*)(base + (size_t)(r1 + c0) * CO);
            bf16x4 s11 = *(const bf16x4*)(base + (size_t)(r1 + c1) * CO);
            bf16x4 pv;
#pragma unroll
            for (int r = 0; r < 4; r++){
                float v = w4.x * (float)s00[r] + w4.y * (float)s01[r]
                        + w4.z * (float)s10[r] + w4.w * (float)s11[r];
                pv[r] = (__bf16)v;
            }
            int oct_sw = (j >> 1) ^ (px & 7);
            *(bf16x4*)&Ab[px * 64 + oct_sw * 8 + (j & 1) * 4] = pv;
        }
        __syncthreads();
        const bf16x8* ap = (const bf16x8*)Ab;
        const bf16x8* bp = (const bf16x8*)Bb;
#pragma unroll
        for (int ks = 0; ks < 2; ks++){
            bf16x8 af[4], bfr[4];
#pragma unroll
            for (int mi = 0; mi < 4; mi++){
                int px = wm * 64 + mi * 16 + m;
                af[mi] = ap[px * 8 + ((ks * 4 + quad) ^ (px & 7))];
            }
#pragma unroll
            for (int ni = 0; ni < 4; ni++){
                int oc = wn * 64 + ni * 16 + m;
                bfr[ni] = bp[oc * 8 + ((ks * 4 + quad) ^ (oc & 7))];
            }
#pragma unroll
            for (int mi = 0; mi < 4; mi++)
#pragma unroll
                for (int ni = 0; ni < 4; ni++)
                    acc[mi][ni] = __builtin_amdgcn_mfma_f32_16x16x32_bf16(
                        af[mi], bfr[ni], acc[mi][ni], 0, 0, 0);
        }
    }
    // epilogue + bias
#pragma unroll
    for (int mi = 0; mi < 4; mi++){
        int p0 = wm * 64 + mi * 16 + quad * 4;
#pragma unroll
        for (int ni = 0; ni < 4; ni++){
            int oc = wn * 64 + ni * 16 + m;
            float bias = def_b[oc];
#pragma unroll
            for (int r = 0; r < 4; r++)
                y[(size_t)(rowpix + p0 + r) * CO + oc] = f2b(acc[mi][ni][r] + bias);
        }
    }
}

// ------------- BN2 apply + relu + NHWC->NCHW via LDS transpose -------------
__global__ __launch_bounds__(256) void k_final(const bf16* __restrict__ yb,
                                               const float* __restrict__ sc,
                                               float* __restrict__ out){
    __shared__ unsigned short tile[128 * 129];
    int t = threadIdx.x;
    int yrow = blockIdx.x % H, b = blockIdx.x / H;
    int rowbase = b * HW + yrow * W;
    const unsigned short* src = (const unsigned short*)yb;
    for (int it = 0; it < 64; it++){
        int idx = it * 256 + t;
        int c = idx & 127, px = idx >> 7;
        tile[px * 129 + c] = src[(size_t)(rowbase + px) * CO + c];
    }
    __syncthreads();
    for (int it = 0; it < 64; it++){
        int idx = it * 256 + t;
        int xw = idx & 127, o = idx >> 7;
        unsigned short u = tile[xw * 129 + o];
        float v = (float)(*(const __bf16*)&u);
        v = v * sc[o] + sc[128 + o];
        out[(((size_t)b * CO + o) * H + yrow) * W + xw] = v > 0.f ? v : 0.f;
    }
}

extern "C" void kernel_launch(void* const* d_in, const int* in_sizes, int n_in,
                              void* d_out, int out_size, void* d_ws, size_t ws_size,
                              hipStream_t stream){
    const float* x      = (const float*)d_in[0];
    const float* skip   = (const float*)d_in[1];
    const float* conv1w = (const float*)d_in[2];
    const float* bn1g   = (const float*)d_in[3];
    const float* bn1b   = (const float*)d_in[4];
    const float* offw   = (const float*)d_in[5];
    const float* offb   = (const float*)d_in[6];
    const float* defw   = (const float*)d_in[7];
    const float* defb   = (const float*)d_in[8];
    const float* bn2g   = (const float*)d_in[9];
    const float* bn2b   = (const float*)d_in[10];
    float* out = (float*)d_out;

    char* ws = (char*)d_ws;
    size_t off_bytes = 0;
    auto alloc = [&](size_t bytes) -> void* {
        void* p = ws + off_bytes;
        off_bytes += (bytes + 255) & ~(size_t)255;
        return p;
    };
    const size_t catp_elems = (size_t)NB * WP * WP * CCAT;
    const size_t hp_elems   = (size_t)NB * WP * WP * CO;
    bf16*  catp  = (bf16*) alloc(catp_elems * 2);            // 51.9 MB
    bf16*  hp    = (bf16*) alloc(hp_elems * 2);              // 17.3 MB (conv1 out -> h, padded)
    bf16*  offs  = (bf16*) alloc((size_t)NPIX * 18 * 2);     //  2.4 MB
    bf16*  yb    = (bf16*) alloc((size_t)NPIX * CO * 2);     // 16.8 MB
    bf16*  wbt   = (bf16*) alloc((size_t)CO * K1 * 2);       // conv1 W^T
    bf16*  wob   = (bf16*) alloc((size_t)32 * KD * 2);       // off W^T (padded 32)
    bf16*  wdb   = (bf16*) alloc((size_t)CO * KD * 2);       // deform W^T
    float* sums1 = (float*)alloc(256 * 4);
    float* sums2 = (float*)alloc(256 * 4);
    float* sc1   = (float*)alloc(256 * 4);
    float* sc2   = (float*)alloc(256 * 4);

    k_zero<<<1, 256, 0, stream>>>(sums1, 256);
    k_zero<<<1, 256, 0, stream>>>(sums2, 256);
    k_zero4<<<2048, 256, 0, stream>>>((float4*)catp, (int)(catp_elems * 2 / 16));
    k_zero4<<<1024, 256, 0, stream>>>((float4*)hp,   (int)(hp_elems * 2 / 16));

    k_build_cat<<<(NPIX * CCAT + 255) / 256, 256, 0, stream>>>(x, skip, catp);
    k_tr_w1b <<<(CO * K1 + 255) / 256, 256, 0, stream>>>(conv1w, wbt);
    k_tr_offb<<<(32 * KD + 255) / 256, 256, 0, stream>>>(offw, wob);
    k_tr_defb<<<(CO * KD + 255) / 256, 256, 0, stream>>>(defw, wdb);

    k_conv1_mfma<<<NB * H, 256, 0, stream>>>(catp, wbt, hp);

    k_bn_stats_pad<<<NPIX / 256, 256, 0, stream>>>(hp, sums1);
    k_bn_fin<<<1, 128, 0, stream>>>(sums1, bn1g, bn1b, sc1);
    k_bn_apply_pad<<<(NPIX * CO + 255) / 256, 256, 0, stream>>>(hp, sc1);

    k_conv_off_mfma<<<NB * H, 256, 0, stream>>>(hp, wob, offb, offs);

    k_deform_mfma<<<NB * H, 256, 0, stream>>>(hp, offs, wdb, defb, yb);

    k_bn_stats<<<NPIX / 256, 256, 0, stream>>>(yb, sums2);
    k_bn_fin<<<1, 128, 0, stream>>>(sums2, bn2g, bn2b, sc2);
    k_final<<<NB * H, 256, 0, stream>>>(yb, sc2, out);
}

// Round 5
// 416.494 us; speedup vs baseline: 14.6858x; 1.3408x over previous
//
#include <hip/hip_runtime.h>
#include <hip/hip_bf16.h>

typedef __hip_bfloat16 bf16;
typedef __bf16 bf16x8 __attribute__((ext_vector_type(8)));
typedef __bf16 bf16x4 __attribute__((ext_vector_type(4)));
typedef float  f32x4  __attribute__((ext_vector_type(4)));

constexpr int NB   = 4;
constexpr int H    = 128;
constexpr int W    = 128;
constexpr int HW   = H * W;
constexpr int NPIX = NB * HW;        // 65536
constexpr int CCAT = 384;
constexpr int CSKIP= 128;
constexpr int CIN  = 256;
constexpr int CO   = 128;
constexpr int HS   = 64;
constexpr int WP   = 130;            // padded H/W
constexpr int K1   = 3456;           // conv1 GEMM K
constexpr int KD   = 1152;           // deform/off GEMM K
constexpr int NBORD= 2 * WP + 2 * (WP - 2);   // 516 border px per image
constexpr float EPS = 1e-5f;

__device__ __forceinline__ float b2f(bf16 v){ return __bfloat162float(v); }
__device__ __forceinline__ bf16  f2b(float v){ return __float2bfloat16(v); }

__device__ __forceinline__ void async_copy16(const void* g, void* s){
    __builtin_amdgcn_global_load_lds((const __attribute__((address_space(1))) void*)g,
                                     (__attribute__((address_space(3))) void*)s, 16, 0, 0);
}

// ---------------- zero helpers ----------------
__global__ void k_zero(float* p, int n){
    int i = blockIdx.x * blockDim.x + threadIdx.x;
    if (i < n) p[i] = 0.f;
}

// map border index 0..515 -> (y,x) on the WPxWP frame
__device__ __forceinline__ void border_yx(int p, int& y, int& x){
    if (p < WP)             { y = 0;        x = p; }
    else if (p < 2 * WP)    { y = WP - 1;   x = p - WP; }
    else if (p < 2 * WP + (WP - 2)) { y = p - 2 * WP + 1;          x = 0; }
    else                    { y = p - (2 * WP + (WP - 2)) + 1;     x = WP - 1; }
}

__global__ void k_border_cat(bf16* __restrict__ catp){
    int i = blockIdx.x * blockDim.x + threadIdx.x;
    if (i >= NB * NBORD * CCAT) return;
    int c = i % CCAT; int r = i / CCAT;
    int p = r % NBORD, b = r / NBORD;
    int y, x; border_yx(p, y, x);
    catp[(((size_t)b * WP + y) * WP + x) * CCAT + c] = f2b(0.f);
}
__global__ void k_border_hp(bf16* __restrict__ hp){
    int i = blockIdx.x * blockDim.x + threadIdx.x;
    if (i >= NB * NBORD * CO) return;
    int c = i % CO; int r = i / CO;
    int p = r % NBORD, b = r / NBORD;
    int y, x; border_yx(p, y, x);
    hp[(((size_t)b * WP + y) * WP + x) * CO + c] = f2b(0.f);
}

// ------------- build cat interior via LDS transpose -------------
// one block per (b, y): fill tile[x][c-chunk] with lanes along x (coalesced NCHW
// reads), then write NHWC with lanes along c (coalesced 4B stores).
__global__ __launch_bounds__(256) void k_build_cat2(const float* __restrict__ x,
                                                    const float* __restrict__ skip,
                                                    bf16* __restrict__ catp){
    constexpr int TS = 66;               // LDS row stride in shorts (bank-spread)
    __shared__ bf16 tile[128 * TS];
    int t  = threadIdx.x;
    int y  = blockIdx.x % H, b = blockIdx.x / H;
    int xx = t & 127, cp = t >> 7;       // fill mapping: lane=x, cp=0/1

    float cy = (y * 63.0f) / 127.0f;
    int   y0 = (int)cy;
    int   y1 = min(y0 + 1, HS - 1);
    float wy = cy - y0;
    float cxf = (xx * 63.0f) / 127.0f;
    int   x0 = (int)cxf;
    int   x1 = min(x0 + 1, HS - 1);
    float wx = cxf - x0;

    bf16* orow = catp + (((size_t)b * WP + y + 1) * WP + 1) * CCAT;

    for (int chunk = 0; chunk < 6; chunk++){
        int cbase = chunk * 64;
        if (chunk >= 1) __syncthreads();           // protect tile reuse
        if (chunk < 2){
            const float* sb = skip + ((size_t)(b * CSKIP + cbase + cp * 32) * H + y) * W;
#pragma unroll
            for (int i = 0; i < 32; i++)
                tile[xx * TS + cp * 32 + i] = f2b(sb[(size_t)i * HW + xx]);
        } else {
            int icb = (chunk - 2) * 64 + cp * 32;
            const float* xr0 = x + ((size_t)(b * CIN + icb) * HS + y0) * HS;
            const float* xr1 = x + ((size_t)(b * CIN + icb) * HS + y1) * HS;
#pragma unroll
            for (int i = 0; i < 32; i++){
                const float* r0 = xr0 + (size_t)i * HS * HS;
                const float* r1 = xr1 + (size_t)i * HS * HS;
                float v0 = r0[x0] * (1 - wx) + r0[x1] * wx;
                float v1 = r1[x0] * (1 - wx) + r1[x1] * wx;
                tile[xx * TS + cp * 32 + i] = f2b(v0 * (1 - wy) + v1 * wy);
            }
        }
        __syncthreads();
        // write phase: 4B per thread, lanes along c
        int cc2 = (t & 31) * 2;
        int px0 = t >> 5;                  // 0..7
#pragma unroll
        for (int pp = 0; pp < 16; pp++){
            int px = pp * 8 + px0;
            unsigned int v = *(const unsigned int*)&tile[px * TS + cc2];
            *(unsigned int*)&orow[(size_t)px * CCAT + cbase + cc2] = v;
        }
    }
}

// ------------- weight transposes -------------
__global__ void k_tr_w1b(const float* __restrict__ w, bf16* __restrict__ wt){
    int i = blockIdx.x * blockDim.x + threadIdx.x;
    if (i >= CO * K1) return;
    int k  = i % K1;
    int oc = i / K1;
    int ky = k / 1152; int r = k % 1152; int kx = r / 384; int ic = r % 384;
    wt[i] = f2b(w[((oc * CCAT + ic) * 3 + ky) * 3 + kx]);
}
__global__ void k_tr_offb(const float* __restrict__ w, bf16* __restrict__ wt){
    int i = blockIdx.x * blockDim.x + threadIdx.x;
    if (i >= 32 * KD) return;
    int kk = i % KD, o = i / KD;
    int ky = kk / 384; int r = kk % 384; int kx = r >> 7; int ic = r & 127;
    wt[i] = (o < 18) ? f2b(w[((o * CO + ic) * 3 + ky) * 3 + kx]) : f2b(0.f);
}
__global__ void k_tr_defb(const float* __restrict__ w, bf16* __restrict__ wt){
    int i = blockIdx.x * blockDim.x + threadIdx.x;
    if (i >= CO * KD) return;
    int kk = i % KD, o = i / KD;
    int kp = kk >> 7, c = kk & 127;
    wt[i] = f2b(w[(o * CO + c) * 9 + kp]);
}

// ------------- conv1 implicit-GEMM MFMA: catp -> hp (padded, pre-BN) -------------
__global__ __launch_bounds__(256) void k_conv1_mfma(const bf16* __restrict__ catp,
                                                    const bf16* __restrict__ wbt,
                                                    bf16* __restrict__ hp){
    __shared__ unsigned short Ab[128 * 64];
    __shared__ unsigned short Bb[128 * 64];
    int t = threadIdx.x;
    int l = t & 63, w = t >> 6;
    int y = blockIdx.x % H, b = blockIdx.x / H;

    int pr   = l >> 3;
    int koct = (l & 7) ^ pr;
    int m    = l & 15, quad = l >> 4;
    int wm   = w & 1,  wn   = w >> 1;

    f32x4 acc[4][4];
#pragma unroll
    for (int i = 0; i < 4; i++)
#pragma unroll
        for (int j = 0; j < 4; j++) acc[i][j] = f32x4{0.f, 0.f, 0.f, 0.f};

    const size_t rowStride = (size_t)WP * CCAT;
    for (int ky = 0; ky < 3; ky++){
        const bf16* Arow = catp + ((size_t)(b * WP) + y + ky) * rowStride;
        for (int kc = 0; kc < 18; kc++){
            int c0 = kc / 6, r0 = (kc % 6) * 64;
            __syncthreads();
#pragma unroll
            for (int i = 0; i < 4; i++){
                int px = w * 32 + i * 8 + pr;
                async_copy16(Arow + (size_t)(px + c0) * CCAT + r0 + koct * 8,
                             &Ab[(w * 32 + i * 8) * 64]);
            }
            int kg = ky * 1152 + kc * 64;
#pragma unroll
            for (int i = 0; i < 4; i++){
                int oc = w * 32 + i * 8 + pr;
                async_copy16(wbt + (size_t)oc * K1 + kg + koct * 8,
                             &Bb[(w * 32 + i * 8) * 64]);
            }
            __syncthreads();
            const bf16x8* ap = (const bf16x8*)Ab;
            const bf16x8* bp = (const bf16x8*)Bb;
#pragma unroll
            for (int ks = 0; ks < 2; ks++){
                bf16x8 af[4], bfr[4];
#pragma unroll
                for (int mi = 0; mi < 4; mi++){
                    int px = wm * 64 + mi * 16 + m;
                    af[mi] = ap[px * 8 + ((ks * 4 + quad) ^ (px & 7))];
                }
#pragma unroll
                for (int ni = 0; ni < 4; ni++){
                    int oc = wn * 64 + ni * 16 + m;
                    bfr[ni] = bp[oc * 8 + ((ks * 4 + quad) ^ (oc & 7))];
                }
#pragma unroll
                for (int mi = 0; mi < 4; mi++)
#pragma unroll
                    for (int ni = 0; ni < 4; ni++)
                        acc[mi][ni] = __builtin_amdgcn_mfma_f32_16x16x32_bf16(
                            af[mi], bfr[ni], acc[mi][ni], 0, 0, 0);
            }
        }
    }
    size_t obase = (((size_t)b * WP + y + 1) * WP + 1) * CO;
#pragma unroll
    for (int mi = 0; mi < 4; mi++){
        int p0 = wm * 64 + mi * 16 + quad * 4;
#pragma unroll
        for (int ni = 0; ni < 4; ni++){
            int oc = wn * 64 + ni * 16 + m;
#pragma unroll
            for (int r = 0; r < 4; r++)
                hp[obase + (size_t)(p0 + r) * CO + oc] = f2b(acc[mi][ni][r]);
        }
    }
}

// ------------- BN stats over padded hp interior -------------
__global__ __launch_bounds__(256) void k_bn_stats_pad(const bf16* __restrict__ t,
                                                      float* __restrict__ sums){
    int c    = threadIdx.x & 127;
    int half = threadIdx.x >> 7;
    int pix0 = blockIdx.x * 256;
    float s = 0.f, q = 0.f;
    for (int p = half; p < 256; p += 2){
        int pix = pix0 + p;
        int xw = pix & 127, yh = (pix >> 7) & 127, b = pix >> 14;
        float v = b2f(t[(((size_t)b * WP + yh + 1) * WP + xw + 1) * CO + c]);
        s += v; q += v * v;
    }
    __shared__ float ls[256], lq[256];
    ls[threadIdx.x] = s; lq[threadIdx.x] = q;
    __syncthreads();
    if (threadIdx.x < 128){
        atomicAdd(&sums[c],       ls[threadIdx.x] + ls[threadIdx.x + 128]);
        atomicAdd(&sums[128 + c], lq[threadIdx.x] + lq[threadIdx.x + 128]);
    }
}
__global__ __launch_bounds__(256) void k_bn_stats(const bf16* __restrict__ t,
                                                  float* __restrict__ sums){
    int c    = threadIdx.x & 127;
    int half = threadIdx.x >> 7;
    int pix0 = blockIdx.x * 256;
    float s = 0.f, q = 0.f;
    for (int p = half; p < 256; p += 2){
        float v = b2f(t[(size_t)(pix0 + p) * CO + c]);
        s += v; q += v * v;
    }
    __shared__ float ls[256], lq[256];
    ls[threadIdx.x] = s; lq[threadIdx.x] = q;
    __syncthreads();
    if (threadIdx.x < 128){
        atomicAdd(&sums[c],       ls[threadIdx.x] + ls[threadIdx.x + 128]);
        atomicAdd(&sums[128 + c], lq[threadIdx.x] + lq[threadIdx.x + 128]);
    }
}

__global__ void k_bn_fin(const float* __restrict__ sums, const float* __restrict__ g,
                         const float* __restrict__ bb, float* __restrict__ sc){
    int c = threadIdx.x;
    if (c >= CO) return;
    float n    = (float)NPIX;
    float mean = sums[c] / n;
    float var  = sums[128 + c] / n - mean * mean;
    float scale = g[c] * rsqrtf(var + EPS);
    sc[c]       = scale;
    sc[128 + c] = bb[c] - mean * scale;
}

__global__ void k_bn_apply_pad(bf16* __restrict__ t, const float* __restrict__ sc){
    int i = blockIdx.x * blockDim.x + threadIdx.x;
    if (i >= NPIX * CO) return;
    int c = i & 127;
    int pix = i >> 7;
    int xw = pix & 127, yh = (pix >> 7) & 127, b = pix >> 14;
    size_t a = (((size_t)b * WP + yh + 1) * WP + xw + 1) * CO + c;
    float v = b2f(t[a]) * sc[c] + sc[128 + c];
    t[a] = f2b(v > 0.f ? v : 0.f);
}

// ------------- offset conv as MFMA: hp -> offs[pix][18] -------------
__global__ __launch_bounds__(256) void k_conv_off_mfma(const bf16* __restrict__ hp,
                                                       const bf16* __restrict__ wob,
                                                       const float* __restrict__ off_b,
                                                       bf16* __restrict__ offs){
    __shared__ unsigned short Ab[128 * 64];
    __shared__ unsigned short Bb[32 * 64];
    int t = threadIdx.x, l = t & 63, w = t >> 6;
    int y = blockIdx.x % H, b = blockIdx.x / H;
    int pr = l >> 3, koct = (l & 7) ^ pr;
    int m = l & 15, quad = l >> 4;
    int wm = w & 1, wn = w >> 1;

    f32x4 acc[4];
#pragma unroll
    for (int i = 0; i < 4; i++) acc[i] = f32x4{0.f, 0.f, 0.f, 0.f};

    const size_t rowStride = (size_t)WP * CO;
    for (int ky = 0; ky < 3; ky++){
        const bf16* Arow = hp + ((size_t)(b * WP) + y + ky) * rowStride;
        for (int kc = 0; kc < 6; kc++){
            int kx = kc >> 1, r0 = (kc & 1) * 64;
            __syncthreads();
#pragma unroll
            for (int i = 0; i < 4; i++){
                int px = w * 32 + i * 8 + pr;
                async_copy16(Arow + (size_t)(px + kx) * CO + r0 + koct * 8,
                             &Ab[(w * 32 + i * 8) * 64]);
            }
            int kg = ky * 384 + kx * 128 + r0;
            async_copy16(wob + (size_t)(w * 8 + pr) * KD + kg + koct * 8,
                         &Bb[(w * 8) * 64]);
            __syncthreads();
            const bf16x8* ap = (const bf16x8*)Ab;
            const bf16x8* bp = (const bf16x8*)Bb;
#pragma unroll
            for (int ks = 0; ks < 2; ks++){
                int oc = wn * 16 + m;
                bf16x8 bfr = bp[oc * 8 + ((ks * 4 + quad) ^ (oc & 7))];
#pragma unroll
                for (int mi = 0; mi < 4; mi++){
                    int px = wm * 64 + mi * 16 + m;
                    bf16x8 af = ap[px * 8 + ((ks * 4 + quad) ^ (px & 7))];
                    acc[mi] = __builtin_amdgcn_mfma_f32_16x16x32_bf16(af, bfr, acc[mi], 0, 0, 0);
                }
            }
        }
    }
    int oc = wn * 16 + m;
    if (oc < 18){
        float bias = off_b[oc];
        int rowpix = b * HW + y * W;
#pragma unroll
        for (int mi = 0; mi < 4; mi++){
            int p0 = wm * 64 + mi * 16 + quad * 4;
#pragma unroll
            for (int r = 0; r < 4; r++)
                offs[(size_t)(rowpix + p0 + r) * 18 + oc] = f2b(acc[mi][r] + bias);
        }
    }
}

// ------------- deform: generate sampled A in LDS + MFMA GEMM -------------
__global__ __launch_bounds__(256) void k_deform_mfma(const bf16* __restrict__ hp,
                                                     const bf16* __restrict__ offs,
                                                     const bf16* __restrict__ wdb,
                                                     const float* __restrict__ def_b,
                                                     bf16* __restrict__ y){
    __shared__ unsigned short Ab[128 * 64];
    __shared__ unsigned short Bb[128 * 64];
    __shared__ int2   sc_yx[9 * 128];
    __shared__ float4 sc_w[9 * 128];

    int t = threadIdx.x, l = t & 63, w = t >> 6;
    int yrow = blockIdx.x % H, b = blockIdx.x / H;
    int rowpix = b * HW + yrow * W;

    for (int idx = t; idx < 9 * 128; idx += 256){
        int kp = idx >> 7, px = idx & 127;
        float dy = b2f(offs[(size_t)(rowpix + px) * 18 + 2 * kp]);
        float dx = b2f(offs[(size_t)(rowpix + px) * 18 + 2 * kp + 1]);
        float py = yrow + (kp / 3 - 1) + dy;
        float pxx = px + (kp % 3 - 1) + dx;
        float fy = floorf(py), fx = floorf(pxx);
        float wy = py - fy, wx = pxx - fx;
        int y0 = (int)fy, x0 = (int)fx;
        bool vy0 = (y0 >= 0) && (y0 < H);
        bool vy1 = (y0 + 1 >= 0) && (y0 + 1 < H);
        bool vx0 = (x0 >= 0) && (x0 < W);
        bool vx1 = (x0 + 1 >= 0) && (x0 + 1 < W);
        int y0c = min(max(y0, 0), H - 1),     y1c = min(max(y0 + 1, 0), H - 1);
        int x0c = min(max(x0, 0), W - 1),     x1c = min(max(x0 + 1, 0), W - 1);
        sc_yx[idx] = make_int2(((y0c + 1) * WP) | (((y1c + 1) * WP) << 16),
                               (x0c + 1) | ((x1c + 1) << 16));
        sc_w[idx] = make_float4((1 - wy) * (1 - wx) * (float)(vy0 && vx0),
                                (1 - wy) * wx       * (float)(vy0 && vx1),
                                wy * (1 - wx)       * (float)(vy1 && vx0),
                                wy * wx             * (float)(vy1 && vx1));
    }
    __syncthreads();

    int pr = l >> 3, koct = (l & 7) ^ pr;
    int m = l & 15, quad = l >> 4;
    int wm = w & 1, wn = w >> 1;
    int g = l >> 4, j = l & 15;

    f32x4 acc[4][4];
#pragma unroll
    for (int i = 0; i < 4; i++)
#pragma unroll
        for (int jj = 0; jj < 4; jj++) acc[i][jj] = f32x4{0.f, 0.f, 0.f, 0.f};

    const bf16* hpb = hp + (size_t)b * WP * WP * CO;

    for (int kc = 0; kc < 18; kc++){
        int kp = kc >> 1, ch = (kc & 1) * 64;
        __syncthreads();
        int kg = kp * 128 + ch;
#pragma unroll
        for (int i = 0; i < 4; i++){
            int oc = w * 32 + i * 8 + pr;
            async_copy16(wdb + (size_t)oc * KD + kg + koct * 8,
                         &Bb[(w * 32 + i * 8) * 64]);
        }
        int cb = ch + j * 4;
#pragma unroll
        for (int p = 0; p < 8; p++){
            int px = w * 32 + g * 8 + p;
            int idx = kp * 128 + px;
            int2 yx = sc_yx[idx];
            float4 w4 = sc_w[idx];
            int r0 = yx.x & 0xffff, r1 = ((unsigned)yx.x) >> 16;
            int c0 = yx.y & 0xffff, c1 = ((unsigned)yx.y) >> 16;
            const bf16* base = hpb + cb;
            bf16x4 s00 = *(const bf16x4*)(base + (size_t)(r0 + c0) * CO);
            bf16x4 s01 = *(const bf16x4*)(base + (size_t)(r0 + c1) * CO);
            bf16x4 s10 = *(const bf16x4*)(base + (size_t)(r1 + c0) * CO);
            bf16x4 s11 = *(const bf16x4*)(base + (size_t)(r1 + c1) * CO);
            bf16x4 pv;
#pragma unroll
            for (int r = 0; r < 4; r++){
                float v = w4.x * (float)s00[r] + w4.y * (float)s01[r]
                        + w4.z * (float)s10[r] + w4.w * (float)s11[r];
                pv[r] = (__bf16)v;
            }
            int oct_sw = (j >> 1) ^ (px & 7);
            *(bf16x4*)&Ab[px * 64 + oct_sw * 8 + (j & 1) * 4] = pv;
        }
        __syncthreads();
        const bf16x8* ap = (const bf16x8*)Ab;
        const bf16x8* bp = (const bf16x8*)Bb;
#pragma unroll
        for (int ks = 0; ks < 2; ks++){
            bf16x8 af[4], bfr[4];
#pragma unroll
            for (int mi = 0; mi < 4; mi++){
                int px = wm * 64 + mi * 16 + m;
                af[mi] = ap[px * 8 + ((ks * 4 + quad) ^ (px & 7))];
            }
#pragma unroll
            for (int ni = 0; ni < 4; ni++){
                int oc = wn * 64 + ni * 16 + m;
                bfr[ni] = bp[oc * 8 + ((ks * 4 + quad) ^ (oc & 7))];
            }
#pragma unroll
            for (int mi = 0; mi < 4; mi++)
#pragma unroll
                for (int ni = 0; ni < 4; ni++)
                    acc[mi][ni] = __builtin_amdgcn_mfma_f32_16x16x32_bf16(
                        af[mi], bfr[ni], acc[mi][ni], 0, 0, 0);
        }
    }
#pragma unroll
    for (int mi = 0; mi < 4; mi++){
        int p0 = wm * 64 + mi * 16 + quad * 4;
#pragma unroll
        for (int ni = 0; ni < 4; ni++){
            int oc = wn * 64 + ni * 16 + m;
            float bias = def_b[oc];
#pragma unroll
            for (int r = 0; r < 4; r++)
                y[(size_t)(rowpix + p0 + r) * CO + oc] = f2b(acc[mi][ni][r] + bias);
        }
    }
}

// ------------- BN2 apply + relu + NHWC->NCHW via LDS transpose -------------
__global__ __launch_bounds__(256) void k_final(const bf16* __restrict__ yb,
                                               const float* __restrict__ sc,
                                               float* __restrict__ out){
    __shared__ unsigned short tile[128 * 129];
    int t = threadIdx.x;
    int yrow = blockIdx.x % H, b = blockIdx.x / H;
    int rowbase = b * HW + yrow * W;
    const unsigned short* src = (const unsigned short*)yb;
    for (int it = 0; it < 64; it++){
        int idx = it * 256 + t;
        int c = idx & 127, px = idx >> 7;
        tile[px * 129 + c] = src[(size_t)(rowbase + px) * CO + c];
    }
    __syncthreads();
    for (int it = 0; it < 64; it++){
        int idx = it * 256 + t;
        int xw = idx & 127, o = idx >> 7;
        unsigned short u = tile[xw * 129 + o];
        float v = (float)(*(const __bf16*)&u);
        v = v * sc[o] + sc[128 + o];
        out[(((size_t)b * CO + o) * H + yrow) * W + xw] = v > 0.f ? v : 0.f;
    }
}

extern "C" void kernel_launch(void* const* d_in, const int* in_sizes, int n_in,
                              void* d_out, int out_size, void* d_ws, size_t ws_size,
                              hipStream_t stream){
    const float* x      = (const float*)d_in[0];
    const float* skip   = (const float*)d_in[1];
    const float* conv1w = (const float*)d_in[2];
    const float* bn1g   = (const float*)d_in[3];
    const float* bn1b   = (const float*)d_in[4];
    const float* offw   = (const float*)d_in[5];
    const float* offb   = (const float*)d_in[6];
    const float* defw   = (const float*)d_in[7];
    const float* defb   = (const float*)d_in[8];
    const float* bn2g   = (const float*)d_in[9];
    const float* bn2b   = (const float*)d_in[10];
    float* out = (float*)d_out;

    char* ws = (char*)d_ws;
    size_t off_bytes = 0;
    auto alloc = [&](size_t bytes) -> void* {
        void* p = ws + off_bytes;
        off_bytes += (bytes + 255) & ~(size_t)255;
        return p;
    };
    const size_t catp_elems = (size_t)NB * WP * WP * CCAT;
    const size_t hp_elems   = (size_t)NB * WP * WP * CO;
    bf16*  catp  = (bf16*) alloc(catp_elems * 2);            // 51.9 MB
    bf16*  hp    = (bf16*) alloc(hp_elems * 2);              // 17.3 MB
    bf16*  offs  = (bf16*) alloc((size_t)NPIX * 18 * 2);
    bf16*  yb    = (bf16*) alloc((size_t)NPIX * CO * 2);
    bf16*  wbt   = (bf16*) alloc((size_t)CO * K1 * 2);
    bf16*  wob   = (bf16*) alloc((size_t)32 * KD * 2);
    bf16*  wdb   = (bf16*) alloc((size_t)CO * KD * 2);
    float* sums1 = (float*)alloc(256 * 4);
    float* sums2 = (float*)alloc(256 * 4);
    float* sc1   = (float*)alloc(256 * 4);
    float* sc2   = (float*)alloc(256 * 4);

    k_zero<<<1, 256, 0, stream>>>(sums1, 256);
    k_zero<<<1, 256, 0, stream>>>(sums2, 256);
    k_border_cat<<<(NB * NBORD * CCAT + 255) / 256, 256, 0, stream>>>(catp);
    k_border_hp <<<(NB * NBORD * CO   + 255) / 256, 256, 0, stream>>>(hp);

    k_build_cat2<<<NB * H, 256, 0, stream>>>(x, skip, catp);
    k_tr_w1b <<<(CO * K1 + 255) / 256, 256, 0, stream>>>(conv1w, wbt);
    k_tr_offb<<<(32 * KD + 255) / 256, 256, 0, stream>>>(offw, wob);
    k_tr_defb<<<(CO * KD + 255) / 256, 256, 0, stream>>>(defw, wdb);

    k_conv1_mfma<<<NB * H, 256, 0, stream>>>(catp, wbt, hp);

    k_bn_stats_pad<<<NPIX / 256, 256, 0, stream>>>(hp, sums1);
    k_bn_fin<<<1, 128, 0, stream>>>(sums1, bn1g, bn1b, sc1);
    k_bn_apply_pad<<<(NPIX * CO + 255) / 256, 256, 0, stream>>>(hp, sc1);

    k_conv_off_mfma<<<NB * H, 256, 0, stream>>>(hp, wob, offb, offs);

    k_deform_mfma<<<NB * H, 256, 0, stream>>>(hp, offs, wdb, defb, yb);

    k_bn_stats<<<NPIX / 256, 256, 0, stream>>>(yb, sums2);
    k_bn_fin<<<1, 128, 0, stream>>>(sums2, bn2g, bn2b, sc2);
    k_final<<<NB * H, 256, 0, stream>>>(yb, sc2, out);
}

// Round 6
// 349.455 us; speedup vs baseline: 17.5031x; 1.1918x over previous
//
#include <hip/hip_runtime.h>
#include <hip/hip_bf16.h>

typedef __hip_bfloat16 bf16;
typedef __bf16 bf16x8 __attribute__((ext_vector_type(8)));
typedef __bf16 bf16x4 __attribute__((ext_vector_type(4)));
typedef float  f32x4  __attribute__((ext_vector_type(4)));

constexpr int NB   = 4;
constexpr int H    = 128;
constexpr int W    = 128;
constexpr int HW   = H * W;
constexpr int NPIX = NB * HW;        // 65536
constexpr int CCAT = 384;
constexpr int CSKIP= 128;
constexpr int CIN  = 256;
constexpr int CO   = 128;
constexpr int HS   = 64;
constexpr int WP   = 130;            // padded H/W
constexpr int K1   = 3456;           // conv1 GEMM K
constexpr int KD   = 1152;           // deform/off GEMM K
constexpr int NBORD= 2 * WP + 2 * (WP - 2);   // 516 border px per image
constexpr float EPS = 1e-5f;

__device__ __forceinline__ float b2f(bf16 v){ return __bfloat162float(v); }
__device__ __forceinline__ bf16  f2b(float v){ return __float2bfloat16(v); }

__device__ __forceinline__ void async_copy16(const void* g, void* s){
    __builtin_amdgcn_global_load_lds((const __attribute__((address_space(1))) void*)g,
                                     (__attribute__((address_space(3))) void*)s, 16, 0, 0);
}

// XCD-aware row swizzle: blocks dispatch round-robin to 8 XCDs (i%8), so give
// XCD k the 64 consecutive rows [k*64,(k+1)*64) -> 3-row windows hit L2.
__device__ __forceinline__ int swizzle_row(int raw){
    return (raw & 7) * 64 + (raw >> 3);
}

// map border index 0..515 -> (y,x) on the WPxWP frame
__device__ __forceinline__ void border_yx(int p, int& y, int& x){
    if (p < WP)             { y = 0;        x = p; }
    else if (p < 2 * WP)    { y = WP - 1;   x = p - WP; }
    else if (p < 2 * WP + (WP - 2)) { y = p - 2 * WP + 1;          x = 0; }
    else                    { y = p - (2 * WP + (WP - 2)) + 1;     x = WP - 1; }
}

// ------------- prep: zero stat buffers + padded borders -------------
__global__ void k_prep(float* __restrict__ sums, bf16* __restrict__ catp,
                       bf16* __restrict__ hp){
    int i = blockIdx.x * blockDim.x + threadIdx.x;
    int stride = gridDim.x * blockDim.x;
    for (int j = i; j < 512; j += stride) sums[j] = 0.f;
    const int nCat = NB * NBORD * CCAT;
    for (int j = i; j < nCat; j += stride){
        int c = j % CCAT, r = j / CCAT, p = r % NBORD, b = r / NBORD;
        int y, x; border_yx(p, y, x);
        catp[(((size_t)b * WP + y) * WP + x) * CCAT + c] = f2b(0.f);
    }
    const int nHp = NB * NBORD * CO;
    for (int j = i; j < nHp; j += stride){
        int c = j % CO, r = j / CO, p = r % NBORD, b = r / NBORD;
        int y, x; border_yx(p, y, x);
        hp[(((size_t)b * WP + y) * WP + x) * CO + c] = f2b(0.f);
    }
}

// ------------- build cat interior via LDS transpose -------------
__global__ __launch_bounds__(256) void k_build_cat2(const float* __restrict__ x,
                                                    const float* __restrict__ skip,
                                                    bf16* __restrict__ catp){
    constexpr int TS = 66;
    __shared__ bf16 tile[128 * TS];
    int t  = threadIdx.x;
    int y  = blockIdx.x % H, b = blockIdx.x / H;
    int xx = t & 127, cp = t >> 7;

    float cy = (y * 63.0f) / 127.0f;
    int   y0 = (int)cy;
    int   y1 = min(y0 + 1, HS - 1);
    float wy = cy - y0;
    float cxf = (xx * 63.0f) / 127.0f;
    int   x0 = (int)cxf;
    int   x1 = min(x0 + 1, HS - 1);
    float wx = cxf - x0;

    bf16* orow = catp + (((size_t)b * WP + y + 1) * WP + 1) * CCAT;

    for (int chunk = 0; chunk < 6; chunk++){
        int cbase = chunk * 64;
        if (chunk >= 1) __syncthreads();
        if (chunk < 2){
            const float* sb = skip + ((size_t)(b * CSKIP + cbase + cp * 32) * H + y) * W;
#pragma unroll
            for (int i = 0; i < 32; i++)
                tile[xx * TS + cp * 32 + i] = f2b(sb[(size_t)i * HW + xx]);
        } else {
            int icb = (chunk - 2) * 64 + cp * 32;
            const float* xr0 = x + ((size_t)(b * CIN + icb) * HS + y0) * HS;
            const float* xr1 = x + ((size_t)(b * CIN + icb) * HS + y1) * HS;
#pragma unroll
            for (int i = 0; i < 32; i++){
                const float* r0 = xr0 + (size_t)i * HS * HS;
                const float* r1 = xr1 + (size_t)i * HS * HS;
                float v0 = r0[x0] * (1 - wx) + r0[x1] * wx;
                float v1 = r1[x0] * (1 - wx) + r1[x1] * wx;
                tile[xx * TS + cp * 32 + i] = f2b(v0 * (1 - wy) + v1 * wy);
            }
        }
        __syncthreads();
        int cc2 = (t & 31) * 2;
        int px0 = t >> 5;
#pragma unroll
        for (int pp = 0; pp < 16; pp++){
            int px = pp * 8 + px0;
            unsigned int v = *(const unsigned int*)&tile[px * TS + cc2];
            *(unsigned int*)&orow[(size_t)px * CCAT + cbase + cc2] = v;
        }
    }
}

// ------------- all weight transposes in one kernel -------------
__global__ void k_tr_all(const float* __restrict__ w1, const float* __restrict__ wo,
                         const float* __restrict__ wd,
                         bf16* __restrict__ wt1, bf16* __restrict__ wto,
                         bf16* __restrict__ wtd){
    int i = blockIdx.x * blockDim.x + threadIdx.x;
    if (i < CO * K1){
        int k = i % K1, oc = i / K1;
        int ky = k / 1152, r = k % 1152, kx = r / 384, ic = r % 384;
        wt1[i] = f2b(w1[((oc * CCAT + ic) * 3 + ky) * 3 + kx]);
        return;
    }
    i -= CO * K1;
    if (i < 32 * KD){
        int kk = i % KD, o = i / KD;
        int ky = kk / 384, r = kk % 384, kx = r >> 7, ic = r & 127;
        wto[i] = (o < 18) ? f2b(wo[((o * CO + ic) * 3 + ky) * 3 + kx]) : f2b(0.f);
        return;
    }
    i -= 32 * KD;
    if (i < CO * KD){
        int kk = i % KD, o = i / KD;
        int kp = kk >> 7, c = kk & 127;
        wtd[i] = f2b(wd[(o * CO + c) * 9 + kp]);
    }
}

// ------------- conv1 implicit-GEMM MFMA + fused BN1 stats -------------
__global__ __launch_bounds__(256) void k_conv1_mfma(const bf16* __restrict__ catp,
                                                    const bf16* __restrict__ wbt,
                                                    bf16* __restrict__ hp,
                                                    float* __restrict__ sums){
    __shared__ unsigned short Ab[128 * 64];
    __shared__ unsigned short Bb[128 * 64];
    __shared__ float ps[256];
    int t = threadIdx.x;
    int l = t & 63, w = t >> 6;
    int row = swizzle_row(blockIdx.x);
    int y = row & 127, b = row >> 7;

    int pr   = l >> 3;
    int koct = (l & 7) ^ pr;
    int m    = l & 15, quad = l >> 4;
    int wm   = w & 1,  wn   = w >> 1;

    f32x4 acc[4][4];
#pragma unroll
    for (int i = 0; i < 4; i++)
#pragma unroll
        for (int j = 0; j < 4; j++) acc[i][j] = f32x4{0.f, 0.f, 0.f, 0.f};

    const size_t rowStride = (size_t)WP * CCAT;
    for (int ky = 0; ky < 3; ky++){
        const bf16* Arow = catp + ((size_t)(b * WP) + y + ky) * rowStride;
        for (int kc = 0; kc < 18; kc++){
            int c0 = kc / 6, r0 = (kc % 6) * 64;
            __syncthreads();
#pragma unroll
            for (int i = 0; i < 4; i++){
                int px = w * 32 + i * 8 + pr;
                async_copy16(Arow + (size_t)(px + c0) * CCAT + r0 + koct * 8,
                             &Ab[(w * 32 + i * 8) * 64]);
            }
            int kg = ky * 1152 + kc * 64;
#pragma unroll
            for (int i = 0; i < 4; i++){
                int oc = w * 32 + i * 8 + pr;
                async_copy16(wbt + (size_t)oc * K1 + kg + koct * 8,
                             &Bb[(w * 32 + i * 8) * 64]);
            }
            __syncthreads();
            const bf16x8* ap = (const bf16x8*)Ab;
            const bf16x8* bp = (const bf16x8*)Bb;
#pragma unroll
            for (int ks = 0; ks < 2; ks++){
                bf16x8 af[4], bfr[4];
#pragma unroll
                for (int mi = 0; mi < 4; mi++){
                    int px = wm * 64 + mi * 16 + m;
                    af[mi] = ap[px * 8 + ((ks * 4 + quad) ^ (px & 7))];
                }
#pragma unroll
                for (int ni = 0; ni < 4; ni++){
                    int oc = wn * 64 + ni * 16 + m;
                    bfr[ni] = bp[oc * 8 + ((ks * 4 + quad) ^ (oc & 7))];
                }
#pragma unroll
                for (int mi = 0; mi < 4; mi++)
#pragma unroll
                    for (int ni = 0; ni < 4; ni++)
                        acc[mi][ni] = __builtin_amdgcn_mfma_f32_16x16x32_bf16(
                            af[mi], bfr[ni], acc[mi][ni], 0, 0, 0);
            }
        }
    }
    size_t obase = (((size_t)b * WP + y + 1) * WP + 1) * CO;
#pragma unroll
    for (int mi = 0; mi < 4; mi++){
        int p0 = wm * 64 + mi * 16 + quad * 4;
#pragma unroll
        for (int ni = 0; ni < 4; ni++){
            int oc = wn * 64 + ni * 16 + m;
#pragma unroll
            for (int r = 0; r < 4; r++)
                hp[obase + (size_t)(p0 + r) * CO + oc] = f2b(acc[mi][ni][r]);
        }
    }
    // fused BN1 stats
    ps[t] = 0.f;
    __syncthreads();
#pragma unroll
    for (int ni = 0; ni < 4; ni++){
        int ch = wn * 64 + ni * 16 + m;
        float s = 0.f, q = 0.f;
#pragma unroll
        for (int mi = 0; mi < 4; mi++)
#pragma unroll
            for (int r = 0; r < 4; r++){
                float v = acc[mi][ni][r];
                s += v; q += v * v;
            }
        atomicAdd(&ps[ch], s);
        atomicAdd(&ps[128 + ch], q);
    }
    __syncthreads();
    if (t < 128){
        atomicAdd(&sums[t],       ps[t]);
        atomicAdd(&sums[128 + t], ps[128 + t]);
    }
}

// ------------- BN1 apply + relu in place (scale/shift computed inline) -------------
__global__ __launch_bounds__(256) void k_bn_apply_pad(bf16* __restrict__ t,
                                                      const float* __restrict__ sums,
                                                      const float* __restrict__ g,
                                                      const float* __restrict__ bb){
    __shared__ float ssc[256];
    int tt = threadIdx.x;
    if (tt < 128){
        float mean = sums[tt] / (float)NPIX;
        float var  = sums[128 + tt] / (float)NPIX - mean * mean;
        float scale = g[tt] * rsqrtf(var + EPS);
        ssc[tt]       = scale;
        ssc[128 + tt] = bb[tt] - mean * scale;
    }
    __syncthreads();
    int i = blockIdx.x * 256 + tt;
    if (i >= NPIX * CO) return;
    int c = i & 127;
    int pix = i >> 7;
    int xw = pix & 127, yh = (pix >> 7) & 127, b = pix >> 14;
    size_t a = (((size_t)b * WP + yh + 1) * WP + xw + 1) * CO + c;
    float v = b2f(t[a]) * ssc[c] + ssc[128 + c];
    t[a] = f2b(v > 0.f ? v : 0.f);
}

// ------------- offset conv as MFMA: hp -> offs[pix][18] -------------
__global__ __launch_bounds__(256) void k_conv_off_mfma(const bf16* __restrict__ hp,
                                                       const bf16* __restrict__ wob,
                                                       const float* __restrict__ off_b,
                                                       bf16* __restrict__ offs){
    __shared__ unsigned short Ab[128 * 64];
    __shared__ unsigned short Bb[32 * 64];
    int t = threadIdx.x, l = t & 63, w = t >> 6;
    int row = swizzle_row(blockIdx.x);
    int y = row & 127, b = row >> 7;
    int pr = l >> 3, koct = (l & 7) ^ pr;
    int m = l & 15, quad = l >> 4;
    int wm = w & 1, wn = w >> 1;

    f32x4 acc[4];
#pragma unroll
    for (int i = 0; i < 4; i++) acc[i] = f32x4{0.f, 0.f, 0.f, 0.f};

    const size_t rowStride = (size_t)WP * CO;
    for (int ky = 0; ky < 3; ky++){
        const bf16* Arow = hp + ((size_t)(b * WP) + y + ky) * rowStride;
        for (int kc = 0; kc < 6; kc++){
            int kx = kc >> 1, r0 = (kc & 1) * 64;
            __syncthreads();
#pragma unroll
            for (int i = 0; i < 4; i++){
                int px = w * 32 + i * 8 + pr;
                async_copy16(Arow + (size_t)(px + kx) * CO + r0 + koct * 8,
                             &Ab[(w * 32 + i * 8) * 64]);
            }
            int kg = ky * 384 + kx * 128 + r0;
            async_copy16(wob + (size_t)(w * 8 + pr) * KD + kg + koct * 8,
                         &Bb[(w * 8) * 64]);
            __syncthreads();
            const bf16x8* ap = (const bf16x8*)Ab;
            const bf16x8* bp = (const bf16x8*)Bb;
#pragma unroll
            for (int ks = 0; ks < 2; ks++){
                int oc = wn * 16 + m;
                bf16x8 bfr = bp[oc * 8 + ((ks * 4 + quad) ^ (oc & 7))];
#pragma unroll
                for (int mi = 0; mi < 4; mi++){
                    int px = wm * 64 + mi * 16 + m;
                    bf16x8 af = ap[px * 8 + ((ks * 4 + quad) ^ (px & 7))];
                    acc[mi] = __builtin_amdgcn_mfma_f32_16x16x32_bf16(af, bfr, acc[mi], 0, 0, 0);
                }
            }
        }
    }
    int oc = wn * 16 + m;
    if (oc < 18){
        float bias = off_b[oc];
        int rowpix = b * HW + y * W;
#pragma unroll
        for (int mi = 0; mi < 4; mi++){
            int p0 = wm * 64 + mi * 16 + quad * 4;
#pragma unroll
            for (int r = 0; r < 4; r++)
                offs[(size_t)(rowpix + p0 + r) * 18 + oc] = f2b(acc[mi][r] + bias);
        }
    }
}

// ------------- deform: A-gen in LDS + MFMA GEMM + fused BN2 stats -------------
__global__ __launch_bounds__(256) void k_deform_mfma(const bf16* __restrict__ hp,
                                                     const bf16* __restrict__ offs,
                                                     const bf16* __restrict__ wdb,
                                                     const float* __restrict__ def_b,
                                                     bf16* __restrict__ y,
                                                     float* __restrict__ sums){
    __shared__ unsigned short Ab[128 * 64];
    __shared__ unsigned short Bb[128 * 64];
    __shared__ int2   sc_yx[9 * 128];
    __shared__ float4 sc_w[9 * 128];
    __shared__ float  ps[256];

    int t = threadIdx.x, l = t & 63, w = t >> 6;
    int row = swizzle_row(blockIdx.x);
    int yrow = row & 127, b = row >> 7;
    int rowpix = b * HW + yrow * W;

    for (int idx = t; idx < 9 * 128; idx += 256){
        int kp = idx >> 7, px = idx & 127;
        float dy = b2f(offs[(size_t)(rowpix + px) * 18 + 2 * kp]);
        float dx = b2f(offs[(size_t)(rowpix + px) * 18 + 2 * kp + 1]);
        float py = yrow + (kp / 3 - 1) + dy;
        float pxx = px + (kp % 3 - 1) + dx;
        float fy = floorf(py), fx = floorf(pxx);
        float wy = py - fy, wx = pxx - fx;
        int y0 = (int)fy, x0 = (int)fx;
        bool vy0 = (y0 >= 0) && (y0 < H);
        bool vy1 = (y0 + 1 >= 0) && (y0 + 1 < H);
        bool vx0 = (x0 >= 0) && (x0 < W);
        bool vx1 = (x0 + 1 >= 0) && (x0 + 1 < W);
        int y0c = min(max(y0, 0), H - 1),     y1c = min(max(y0 + 1, 0), H - 1);
        int x0c = min(max(x0, 0), W - 1),     x1c = min(max(x0 + 1, 0), W - 1);
        sc_yx[idx] = make_int2(((y0c + 1) * WP) | (((y1c + 1) * WP) << 16),
                               (x0c + 1) | ((x1c + 1) << 16));
        sc_w[idx] = make_float4((1 - wy) * (1 - wx) * (float)(vy0 && vx0),
                                (1 - wy) * wx       * (float)(vy0 && vx1),
                                wy * (1 - wx)       * (float)(vy1 && vx0),
                                wy * wx             * (float)(vy1 && vx1));
    }
    __syncthreads();

    int pr = l >> 3, koct = (l & 7) ^ pr;
    int m = l & 15, quad = l >> 4;
    int wm = w & 1, wn = w >> 1;
    int g = l >> 4, j = l & 15;

    f32x4 acc[4][4];
#pragma unroll
    for (int i = 0; i < 4; i++)
#pragma unroll
        for (int jj = 0; jj < 4; jj++) acc[i][jj] = f32x4{0.f, 0.f, 0.f, 0.f};

    const bf16* hpb = hp + (size_t)b * WP * WP * CO;

    for (int kc = 0; kc < 18; kc++){
        int kp = kc >> 1, ch = (kc & 1) * 64;
        __syncthreads();
        int kg = kp * 128 + ch;
#pragma unroll
        for (int i = 0; i < 4; i++){
            int oc = w * 32 + i * 8 + pr;
            async_copy16(wdb + (size_t)oc * KD + kg + koct * 8,
                         &Bb[(w * 32 + i * 8) * 64]);
        }
        int cb = ch + j * 4;
#pragma unroll
        for (int p = 0; p < 8; p++){
            int px = w * 32 + g * 8 + p;
            int idx = kp * 128 + px;
            int2 yx = sc_yx[idx];
            float4 w4 = sc_w[idx];
            int r0 = yx.x & 0xffff, r1 = ((unsigned)yx.x) >> 16;
            int c0 = yx.y & 0xffff, c1 = ((unsigned)yx.y) >> 16;
            const bf16* base = hpb + cb;
            bf16x4 s00 = *(const bf16x4*)(base + (size_t)(r0 + c0) * CO);
            bf16x4 s01 = *(const bf16x4*)(base + (size_t)(r0 + c1) * CO);
            bf16x4 s10 = *(const bf16x4*)(base + (size_t)(r1 + c0) * CO);
            bf16x4 s11 = *(const bf16x4*)(base + (size_t)(r1 + c1) * CO);
            bf16x4 pv;
#pragma unroll
            for (int r = 0; r < 4; r++){
                float v = w4.x * (float)s00[r] + w4.y * (float)s01[r]
                        + w4.z * (float)s10[r] + w4.w * (float)s11[r];
                pv[r] = (__bf16)v;
            }
            int oct_sw = (j >> 1) ^ (px & 7);
            *(bf16x4*)&Ab[px * 64 + oct_sw * 8 + (j & 1) * 4] = pv;
        }
        __syncthreads();
        const bf16x8* ap = (const bf16x8*)Ab;
        const bf16x8* bp = (const bf16x8*)Bb;
#pragma unroll
        for (int ks = 0; ks < 2; ks++){
            bf16x8 af[4], bfr[4];
#pragma unroll
            for (int mi = 0; mi < 4; mi++){
                int px = wm * 64 + mi * 16 + m;
                af[mi] = ap[px * 8 + ((ks * 4 + quad) ^ (px & 7))];
            }
#pragma unroll
            for (int ni = 0; ni < 4; ni++){
                int oc = wn * 64 + ni * 16 + m;
                bfr[ni] = bp[oc * 8 + ((ks * 4 + quad) ^ (oc & 7))];
            }
#pragma unroll
            for (int mi = 0; mi < 4; mi++)
#pragma unroll
                for (int ni = 0; ni < 4; ni++)
                    acc[mi][ni] = __builtin_amdgcn_mfma_f32_16x16x32_bf16(
                        af[mi], bfr[ni], acc[mi][ni], 0, 0, 0);
        }
    }
#pragma unroll
    for (int mi = 0; mi < 4; mi++){
        int p0 = wm * 64 + mi * 16 + quad * 4;
#pragma unroll
        for (int ni = 0; ni < 4; ni++){
            int oc = wn * 64 + ni * 16 + m;
            float bias = def_b[oc];
#pragma unroll
            for (int r = 0; r < 4; r++)
                y[(size_t)(rowpix + p0 + r) * CO + oc] = f2b(acc[mi][ni][r] + bias);
        }
    }
    // fused BN2 stats
    ps[t] = 0.f;
    __syncthreads();
#pragma unroll
    for (int ni = 0; ni < 4; ni++){
        int ch = wn * 64 + ni * 16 + m;
        float bias = def_b[ch];
        float s = 0.f, q = 0.f;
#pragma unroll
        for (int mi = 0; mi < 4; mi++)
#pragma unroll
            for (int r = 0; r < 4; r++){
                float v = acc[mi][ni][r] + bias;
                s += v; q += v * v;
            }
        atomicAdd(&ps[ch], s);
        atomicAdd(&ps[128 + ch], q);
    }
    __syncthreads();
    if (t < 128){
        atomicAdd(&sums[t],       ps[t]);
        atomicAdd(&sums[128 + t], ps[128 + t]);
    }
}

// ------------- BN2 apply + relu + NHWC->NCHW (scale/shift inline) -------------
__global__ __launch_bounds__(256) void k_final(const bf16* __restrict__ yb,
                                               const float* __restrict__ sums,
                                               const float* __restrict__ g,
                                               const float* __restrict__ bb,
                                               float* __restrict__ out){
    __shared__ unsigned short tile[128 * 129];
    __shared__ float ssc[256];
    int t = threadIdx.x;
    if (t < 128){
        float mean = sums[t] / (float)NPIX;
        float var  = sums[128 + t] / (float)NPIX - mean * mean;
        float scale = g[t] * rsqrtf(var + EPS);
        ssc[t]       = scale;
        ssc[128 + t] = bb[t] - mean * scale;
    }
    int yrow = blockIdx.x % H, b = blockIdx.x / H;
    int rowbase = b * HW + yrow * W;
    const unsigned short* src = (const unsigned short*)yb;
    for (int it = 0; it < 64; it++){
        int idx = it * 256 + t;
        int c = idx & 127, px = idx >> 7;
        tile[px * 129 + c] = src[(size_t)(rowbase + px) * CO + c];
    }
    __syncthreads();
    for (int it = 0; it < 64; it++){
        int idx = it * 256 + t;
        int xw = idx & 127, o = idx >> 7;
        unsigned short u = tile[xw * 129 + o];
        float v = (float)(*(const __bf16*)&u);
        v = v * ssc[o] + ssc[128 + o];
        out[(((size_t)b * CO + o) * H + yrow) * W + xw] = v > 0.f ? v : 0.f;
    }
}

extern "C" void kernel_launch(void* const* d_in, const int* in_sizes, int n_in,
                              void* d_out, int out_size, void* d_ws, size_t ws_size,
                              hipStream_t stream){
    const float* x      = (const float*)d_in[0];
    const float* skip   = (const float*)d_in[1];
    const float* conv1w = (const float*)d_in[2];
    const float* bn1g   = (const float*)d_in[3];
    const float* bn1b   = (const float*)d_in[4];
    const float* offw   = (const float*)d_in[5];
    const float* offb   = (const float*)d_in[6];
    const float* defw   = (const float*)d_in[7];
    const float* defb   = (const float*)d_in[8];
    const float* bn2g   = (const float*)d_in[9];
    const float* bn2b   = (const float*)d_in[10];
    float* out = (float*)d_out;

    char* ws = (char*)d_ws;
    size_t off_bytes = 0;
    auto alloc = [&](size_t bytes) -> void* {
        void* p = ws + off_bytes;
        off_bytes += (bytes + 255) & ~(size_t)255;
        return p;
    };
    const size_t catp_elems = (size_t)NB * WP * WP * CCAT;
    const size_t hp_elems   = (size_t)NB * WP * WP * CO;
    bf16*  catp  = (bf16*) alloc(catp_elems * 2);            // 51.9 MB
    bf16*  hp    = (bf16*) alloc(hp_elems * 2);              // 17.3 MB
    bf16*  offs  = (bf16*) alloc((size_t)NPIX * 18 * 2);
    bf16*  yb    = (bf16*) alloc((size_t)NPIX * CO * 2);
    bf16*  wbt   = (bf16*) alloc((size_t)CO * K1 * 2);
    bf16*  wob   = (bf16*) alloc((size_t)32 * KD * 2);
    bf16*  wdb   = (bf16*) alloc((size_t)CO * KD * 2);
    float* sums  = (float*)alloc(512 * 4);                   // [0:256)=BN1, [256:512)=BN2
    float* sums1 = sums;
    float* sums2 = sums + 256;

    k_prep<<<1024, 256, 0, stream>>>(sums, catp, hp);

    k_build_cat2<<<NB * H, 256, 0, stream>>>(x, skip, catp);

    const int ntr = CO * K1 + 32 * KD + CO * KD;
    k_tr_all<<<(ntr + 255) / 256, 256, 0, stream>>>(conv1w, offw, defw, wbt, wob, wdb);

    k_conv1_mfma<<<NB * H, 256, 0, stream>>>(catp, wbt, hp, sums1);

    k_bn_apply_pad<<<(NPIX * CO + 255) / 256, 256, 0, stream>>>(hp, sums1, bn1g, bn1b);

    k_conv_off_mfma<<<NB * H, 256, 0, stream>>>(hp, wob, offb, offs);

    k_deform_mfma<<<NB * H, 256, 0, stream>>>(hp, offs, wdb, defb, yb, sums2);

    k_final<<<NB * H, 256, 0, stream>>>(yb, sums2, bn2g, bn2b, out);
}